// Round 15
// baseline (121.301 us; speedup 1.0000x reference)
//
#include <hip/hip_runtime.h>

#define HW   3136
#define NCH  64
#define CRED 32
#define NB   8
#define EPSV 1e-5f
#define QS2  7
#define NTB  49      // 64-wide tile blocks per axis
#define NTRI (NTB * (NTB + 1) / 2)   // 1225 upper-triangular tile pairs

// sqrt(log2(e)) — both theta operands scaled => S' = S * log2(e)
#define SQRT_L2E 1.2011224087f
// log2(log2(e))
#define LOG2_L2E 0.5287663729f

typedef __attribute__((ext_vector_type(8))) short short8;
typedef __attribute__((ext_vector_type(4))) float f32x4;
typedef __attribute__((ext_vector_type(2))) float f32x2;
typedef _Float16 half_t;
typedef __attribute__((ext_vector_type(2))) _Float16 half2v;
typedef __attribute__((ext_vector_type(4))) _Float16 half4v;

#define MFMA_B16 __builtin_amdgcn_mfma_f32_16x16x32_bf16

__device__ __forceinline__ unsigned short f2b(float x) {
    union { float f; unsigned u; } v; v.f = x;
    unsigned r = v.u + 0x7fff + ((v.u >> 16) & 1);
    return (unsigned short)(r >> 16);
}

// raw v_exp_f32: 2^x
__device__ __forceinline__ float ex2(float x) {
#if __has_builtin(__builtin_amdgcn_exp2f)
    return __builtin_amdgcn_exp2f(x);
#else
    float r;
    asm volatile("v_exp_f32 %0, %1" : "=v"(r) : "v"(x));
    return r;
#endif
}

// pack two f32 -> bf16x2 in one instruction
__device__ __forceinline__ unsigned cvtpk(float a, float b) {
    unsigned r;
    asm("v_cvt_pk_bf16_f32 %0, %1, %2" : "=v"(r) : "v"(a), "v"(b));
    return r;
}

// ---- K1: conv1x1 + BN1 + ReLU6 -> Gbt[n][i][p] bf16; theta_bf[n][p][c] scaled --
__global__ __launch_bounds__(256) void k1_conv1x1(
    const float* __restrict__ l, const float* __restrict__ w,
    const float* __restrict__ gamma, const float* __restrict__ beta,
    const float* __restrict__ mean, const float* __restrict__ var,
    unsigned short* __restrict__ theta_bf, unsigned short* __restrict__ Gbt)
{
    __shared__ float Wt[NCH][65];   // Wt[c][i]; reused as G-transpose [i][p]
    __shared__ float Lt[NCH][65];   // Lt[c][j]
    const int t  = threadIdx.x;
    const int n  = blockIdx.y;
    const int p0 = blockIdx.x * 64;

    for (int idx = t; idx < NCH * 64; idx += 256) {
        int c = idx >> 6, j = idx & 63;
        Wt[c][j] = w[j * NCH + c];
        Lt[c][j] = l[((size_t)n * NCH + c) * HW + p0 + j];
    }
    __syncthreads();

    // emit theta_bf[n][p0+p][c0..c0+7], pre-scaled by sqrt(log2 e)
    {
        const int p = t >> 2, c0 = (t & 3) * 8;
        unsigned short pk[8];
#pragma unroll
        for (int j = 0; j < 8; ++j) pk[j] = f2b(Lt[c0 + j][p] * SQRT_L2E);
        *(short8*)&theta_bf[((size_t)n * HW + p0 + p) * CRED + c0] = *(short8*)pk;
    }

    const int i   = t & 63;
    const int pj0 = t >> 6;
    const float mu = mean[i];
    const float sc = rsqrtf(var[i] + EPSV) * gamma[i];
    const float bi = beta[i];

    float acc[16];
#pragma unroll
    for (int k = 0; k < 16; ++k) acc[k] = 0.f;
#pragma unroll
    for (int c = 0; c < NCH; ++c) {
        float wci = Wt[c][i];
#pragma unroll
        for (int k = 0; k < 16; ++k) acc[k] += wci * Lt[c][pj0 + 4 * k];
    }
    __syncthreads();   // all reads of Wt done before reuse

#pragma unroll
    for (int k = 0; k < 16; ++k) {
        float y = (acc[k] - mu) * sc + bi;
        y = fminf(fmaxf(y, 0.f), 6.f);
        Wt[i][pj0 + 4 * k] = y;        // transpose buffer [i][p]
    }
    __syncthreads();

    {
        const int ir = t >> 2, pc = (t & 3) * 16;
        unsigned short pk[16];
#pragma unroll
        for (int j = 0; j < 16; ++j) pk[j] = f2b(Wt[ir][pc + j]);
        unsigned short* dst = &Gbt[((size_t)n * NCH + ir) * HW + p0 + pc];
        *(short8*)&dst[0] = *(short8*)&pk[0];
        *(short8*)&dst[8] = *(short8*)&pk[8];
    }
}

// ---- K2s_tri: Z via symmetric upper triangle.  zacc[n][q] += row/col expsums --
// One 64x64 tile (a<=b) per block; no LDS, no barriers. Tile (a,b) row-sums
// feed Z rows of a; by S-symmetry its col-sums feed Z rows of b (skip when a==b
// to avoid double count). 51% of the full-matrix work.
__global__ __launch_bounds__(256) void k2s_tri(
    const unsigned short* __restrict__ theta_bf, float* __restrict__ zacc)
{
    const int t = threadIdx.x, w = t >> 6, lane = t & 63;
    const int lo = lane & 15, hi = lane >> 4;
    const int n = blockIdx.z;

    // decode upper-triangular tile pair (a<=b) from linear index
    int r = blockIdx.x, a = 0;
    while (r >= NTB - a) { r -= NTB - a; ++a; }
    const int b = a + r;

    const unsigned short* thn = theta_bf + (size_t)n * HW * CRED;
    float* zn = zacc + (size_t)n * HW;

    // wave w owns q rows a*64 + w*16 + [0,16)
    const short8 afrag =
        *(const short8*)&thn[(a * 64 + w * 16 + lo) * CRED + hi * 8];

    float zq[4] = {0.f, 0.f, 0.f, 0.f};
#pragma unroll
    for (int ss = 0; ss < 4; ++ss) {
        const short8 bfrag =
            *(const short8*)&thn[(b * 64 + ss * 16 + lo) * CRED + hi * 8];
        f32x4 zero = {0.f, 0.f, 0.f, 0.f};
        f32x4 d = MFMA_B16(afrag, bfrag, zero, 0, 0, 0);
        // D[q = w*16 + hi*4 + reg][p = ss*16 + lo]
        float e0 = ex2(d[0]), e1 = ex2(d[1]), e2 = ex2(d[2]), e3 = ex2(d[3]);
        zq[0] += e0; zq[1] += e1; zq[2] += e2; zq[3] += e3;
        if (a != b) {
            // col sum over this wave's 16 q rows -> Z rows of b
            float c = (e0 + e1) + (e2 + e3);
            c += __shfl_xor(c, 16, 64);
            c += __shfl_xor(c, 32, 64);
            if (hi == 0) atomicAdd(&zn[b * 64 + ss * 16 + lo], c);
        }
    }

    // row sums over the tile's 64 p -> Z rows of a
#pragma unroll
    for (int rr = 0; rr < 4; ++rr) {
        float v = zq[rr];
        v += __shfl_xor(v, 1, 64);
        v += __shfl_xor(v, 2, 64);
        v += __shfl_xor(v, 4, 64);
        v += __shfl_xor(v, 8, 64);
        if (lo == 0) atomicAdd(&zn[a * 64 + w * 16 + hi * 4 + rr], v);
    }
}

// ---- K2c: crow[n][q] = log2(log2 e) - log2(zacc) -------------------------------
__global__ __launch_bounds__(256) void k2c_combine(
    const float* __restrict__ zacc, float* __restrict__ crow)
{
    const int idx = blockIdx.x * 256 + threadIdx.x;
    crow[idx] = LOG2_L2E - __log2f(zacc[idx]);
}

// ---- K3f (MFMA): d = S' + crow (C-op); E = 2^(2^d); PV over q-slice ------------
// EXACT r10/r11/r14-verified kernel (passed 3x, 48.7 us). FROZEN.
__global__ __launch_bounds__(256) void k3f_fused(
    const unsigned short* __restrict__ theta_bf,
    const unsigned short* __restrict__ Gbt,
    const float* __restrict__ crow,
    half_t* __restrict__ Part, float* __restrict__ Zpart)
{
    __shared__ unsigned short Glt[64][76];   // G^T [i][q], pad 76
    __shared__ unsigned short El[64][76];    // E   [p][q] (wave-private rows)

    const int t = threadIdx.x, w = t >> 6, lane = t & 63;
    const int lo = lane & 15, hi = lane >> 4;
    const int n = blockIdx.z, qsp = blockIdx.y;
    const int pblk = blockIdx.x * 64;
    const int pw = w * 16;

    const unsigned short* thn = theta_bf + (size_t)n * HW * CRED;
    const float* crn = crow + (size_t)n * HW;

    // block-invariant theta_p fragment, direct from global
    const short8 bp = *(const short8*)&thn[(pblk + pw + lo) * CRED + hi * 8];

    f32x4 acc[4];
#pragma unroll
    for (int it = 0; it < 4; ++it) acc[it] = (f32x4){0.f, 0.f, 0.f, 0.f};
    float zl = 0.f;

    for (int tile = 0; tile < 7; ++tile) {
        const int qb = qsp * 448 + tile * 64;
        __syncthreads();
        // stage G^T tile: pure bf16 row copy
        {
            const int ir = t >> 2, qoff = (t & 3) * 16;
            const unsigned short* src = &Gbt[((size_t)n * NCH + ir) * HW + qb + qoff];
            *(short8*)&Glt[ir][qoff]     = *(const short8*)&src[0];
            *(short8*)&Glt[ir][qoff + 8] = *(const short8*)&src[8];
        }
        // issue this tile's aq/crow loads here: they complete by the barrier's
        // implicit vmcnt(0) drain, making the S phase pure compute.
        short8 aqr[4];
        f32x4  cvr[4];
#pragma unroll
        for (int s = 0; s < 4; ++s) {
            aqr[s] = *(const short8*)&thn[(qb + s * 16 + lo) * CRED + hi * 8];
            cvr[s] = *(const f32x4*)&crn[qb + s * 16 + hi * 4];
        }
        __syncthreads();

        // S phase: 4 q-subtiles; E rows -> El[p][q]
#pragma unroll
        for (int s = 0; s < 4; ++s) {
            f32x4 d = MFMA_B16(aqr[s], bp, cvr[s], 0, 0, 0);
            float e0 = ex2(ex2(d[0]));
            float e1 = ex2(ex2(d[1]));
            float e2 = ex2(ex2(d[2]));
            float e3 = ex2(ex2(d[3]));
            zl += (e0 + e1) + (e2 + e3);
            unsigned* dst = (unsigned*)&El[pw + lo][s * 16 + hi * 4];
            dst[0] = cvtpk(e0, e1);
            dst[1] = cvtpk(e2, e3);
        }

        // PV phase: acc[it] (D[p][i]) += El[p][q] * Glt[i][q]
#pragma unroll
        for (int ks = 0; ks < 2; ++ks) {
            const short8 ae = *(const short8*)&El[pw + lo][ks * 32 + hi * 8];
#pragma unroll
            for (int it = 0; it < 4; ++it) {
                const short8 bg = *(const short8*)&Glt[it * 16 + lo][ks * 32 + hi * 8];
                acc[it] = MFMA_B16(ae, bg, acc[it], 0, 0, 0);
            }
        }
    }

    // Part[n,qsp][i][p] fp16
    half_t* Pn = Part + ((size_t)n * QS2 + qsp) * (size_t)NCH * HW;
#pragma unroll
    for (int it = 0; it < 4; ++it) {
        half4v h;
        h[0] = (half_t)acc[it][0]; h[1] = (half_t)acc[it][1];
        h[2] = (half_t)acc[it][2]; h[3] = (half_t)acc[it][3];
        *(half4v*)&Pn[(size_t)(it * 16 + lo) * HW + pblk + pw + hi * 4] = h;
    }
    zl += __shfl_xor(zl, 16, 64);
    zl += __shfl_xor(zl, 32, 64);
    if (lane < 16)
        Zpart[((size_t)n * QS2 + qsp) * HW + pblk + pw + lane] = zl;
}

// ---- K34: fused (reduce q-slices + Z-normalize) + depthwise 3x3 + BN2 + res ----
// r14-verified.
__global__ __launch_bounds__(256) void k34_reduce_dw(
    const half_t* __restrict__ Part, const float* __restrict__ Zpart,
    const float* __restrict__ l, const float* __restrict__ wdw,
    const float* __restrict__ gamma, const float* __restrict__ beta,
    const float* __restrict__ mean, const float* __restrict__ var,
    float* __restrict__ out)
{
    __shared__ float op[4][16][56];   // normalized OutPre, halo rows
    __shared__ float zsh[16 * 56];    // 1/Z for halo rows
    __shared__ float wsh[36];         // dw weights for the 4 channels

    const int t    = threadIdx.x;
    const int band = blockIdx.x;            // 0..3, y0 = band*14
    const int i0   = blockIdx.y * 4;        // channel group
    const int n    = blockIdx.z;
    const int y0   = band * 14;

    if (t < 36) wsh[t] = wdw[i0 * 9 + t];

    // 1/Z for halo rows [y0-1, y0+14]
    for (int idx = t; idx < 16 * 56; idx += 256) {
        const int yy = y0 - 1 + idx / 56, x = idx % 56;
        if (yy >= 0 && yy < 56) {
            const int p = yy * 56 + x;
            float z = 0.f;
#pragma unroll
            for (int qs = 0; qs < QS2; ++qs)
                z += Zpart[((size_t)n * QS2 + qs) * HW + p];
            zsh[idx] = 1.f / z;
        }
    }
    __syncthreads();

    // reduce Part over 7 slices, normalize -> op[c][row][x]
    for (int idx = t; idx < 4 * 16 * 56; idx += 256) {
        const int c = idx / (16 * 56), rem = idx % (16 * 56);
        const int yy = y0 - 1 + rem / 56, x = rem % 56;
        if (yy >= 0 && yy < 56) {
            const int p = yy * 56 + x;
            const int i = i0 + c;
            float s = 0.f;
#pragma unroll
            for (int qs = 0; qs < QS2; ++qs)
                s += (float)Part[(((size_t)n * QS2 + qs) * NCH + i) * HW + p];
            op[c][rem / 56][x] = s * zsh[rem];
        }
    }
    __syncthreads();

    // stencil + BN2 + residual for y in [y0, y0+13]
    for (int idx = t; idx < 4 * 14 * 56; idx += 256) {
        const int c = idx / (14 * 56), rem = idx % (14 * 56);
        const int y = y0 + rem / 56, x = rem % 56;
        const int i = i0 + c;

        float acc = 0.f;
#pragma unroll
        for (int dy = -1; dy <= 1; ++dy) {
            const int yy = y + dy;
            if (yy < 0 || yy >= 56) continue;
            const int ly = yy - (y0 - 1);
#pragma unroll
            for (int dx = -1; dx <= 1; ++dx) {
                const int xx = x + dx;
                if (xx < 0 || xx >= 56) continue;
                acc += wsh[c * 9 + (dy + 1) * 3 + (dx + 1)] * op[c][ly][xx];
            }
        }
        const float sc = rsqrtf(var[i] + EPSV) * gamma[i];
        const size_t e = ((size_t)n * NCH + i) * HW + y * 56 + x;
        out[e] = (acc - mean[i]) * sc + beta[i] + l[e];
    }
}

// -------------------------------------------------------------------------------
extern "C" void kernel_launch(void* const* d_in, const int* in_sizes, int n_in,
                              void* d_out, int out_size, void* d_ws, size_t ws_size,
                              hipStream_t stream)
{
    const float* l      = (const float*)d_in[0];
    const float* w_in   = (const float*)d_in[1];
    const float* gamma1 = (const float*)d_in[2];
    const float* beta1  = (const float*)d_in[3];
    const float* mean1  = (const float*)d_in[4];
    const float* var1   = (const float*)d_in[5];
    const float* w_dw   = (const float*)d_in[6];
    const float* gamma2 = (const float*)d_in[7];
    const float* beta2  = (const float*)d_in[8];
    const float* mean2  = (const float*)d_in[9];
    const float* var2   = (const float*)d_in[10];
    float* out = (float*)d_out;

    char* ws = (char*)d_ws;
    const size_t szTheta = (size_t)NB * HW * CRED * 2;        // 1.6 MB
    const size_t szGbt   = (size_t)NB * NCH * HW * 2;         // 3.2 MB
    const size_t szCrow  = (size_t)NB * HW * 4;               // 100 KB
    const size_t szZacc  = (size_t)QS2 * NB * HW * 4;         // slot (only 100KB used)
    const size_t szZp    = (size_t)NB * QS2 * HW * 4;         // 0.7 MB

    unsigned short* theta_bf = (unsigned short*)ws;
    unsigned short* Gbt      = (unsigned short*)(ws + szTheta);
    float* crow   = (float*)(ws + szTheta + szGbt);
    float* zacc   = (float*)(ws + szTheta + szGbt + szCrow);
    float* Zp     = (float*)(ws + szTheta + szGbt + szCrow + szZacc);
    half_t* Part  = (half_t*)(ws + szTheta + szGbt + szCrow + szZacc + szZp);
    (void)ws_size;

    hipMemsetAsync(zacc, 0, (size_t)NB * HW * 4, stream);

    k1_conv1x1<<<dim3(HW / 64, NB), 256, 0, stream>>>(
        l, w_in, gamma1, beta1, mean1, var1, theta_bf, Gbt);

    k2s_tri<<<dim3(NTRI, 1, NB), 256, 0, stream>>>(theta_bf, zacc);

    k2c_combine<<<dim3((NB * HW) / 256), 256, 0, stream>>>(zacc, crow);

    k3f_fused<<<dim3(HW / 64, QS2, NB), 256, 0, stream>>>(
        theta_bf, Gbt, crow, Part, Zp);

    k34_reduce_dw<<<dim3(4, NCH / 4, NB), 256, 0, stream>>>(
        Part, Zp, l, w_dw, gamma2, beta2, mean2, var2, out);
}

// Round 16
// 96.016 us; speedup vs baseline: 1.2633x; 1.2633x over previous
//
#include <hip/hip_runtime.h>

#define HW   3136
#define NCH  64
#define CRED 32
#define NB   8
#define EPSV 1e-5f
#define QS2  7

// sqrt(log2(e)) — both theta operands scaled => S' = S * log2(e)
#define SQRT_L2E 1.2011224087f
// log2(log2(e))
#define LOG2_L2E 0.5287663729f

typedef __attribute__((ext_vector_type(8))) short short8;
typedef __attribute__((ext_vector_type(4))) float f32x4;
typedef __attribute__((ext_vector_type(2))) float f32x2;
typedef _Float16 half_t;
typedef __attribute__((ext_vector_type(2))) _Float16 half2v;
typedef __attribute__((ext_vector_type(4))) _Float16 half4v;

#define MFMA_B16 __builtin_amdgcn_mfma_f32_16x16x32_bf16

__device__ __forceinline__ unsigned short f2b(float x) {
    union { float f; unsigned u; } v; v.f = x;
    unsigned r = v.u + 0x7fff + ((v.u >> 16) & 1);
    return (unsigned short)(r >> 16);
}

// raw v_exp_f32: 2^x
__device__ __forceinline__ float ex2(float x) {
#if __has_builtin(__builtin_amdgcn_exp2f)
    return __builtin_amdgcn_exp2f(x);
#else
    float r;
    asm volatile("v_exp_f32 %0, %1" : "=v"(r) : "v"(x));
    return r;
#endif
}

// pack two f32 -> bf16x2 in one instruction
__device__ __forceinline__ unsigned cvtpk(float a, float b) {
    unsigned r;
    asm("v_cvt_pk_bf16_f32 %0, %1, %2" : "=v"(r) : "v"(a), "v"(b));
    return r;
}

// ---- K1: conv1x1 + BN1 + ReLU6 -> Gbt[n][i][p] bf16; theta_bf[n][p][c] scaled --
__global__ __launch_bounds__(256) void k1_conv1x1(
    const float* __restrict__ l, const float* __restrict__ w,
    const float* __restrict__ gamma, const float* __restrict__ beta,
    const float* __restrict__ mean, const float* __restrict__ var,
    unsigned short* __restrict__ theta_bf, unsigned short* __restrict__ Gbt)
{
    __shared__ float Wt[NCH][65];   // Wt[c][i]; reused as G-transpose [i][p]
    __shared__ float Lt[NCH][65];   // Lt[c][j]
    const int t  = threadIdx.x;
    const int n  = blockIdx.y;
    const int p0 = blockIdx.x * 64;

    for (int idx = t; idx < NCH * 64; idx += 256) {
        int c = idx >> 6, j = idx & 63;
        Wt[c][j] = w[j * NCH + c];
        Lt[c][j] = l[((size_t)n * NCH + c) * HW + p0 + j];
    }
    __syncthreads();

    // emit theta_bf[n][p0+p][c0..c0+7], pre-scaled by sqrt(log2 e)
    {
        const int p = t >> 2, c0 = (t & 3) * 8;
        unsigned short pk[8];
#pragma unroll
        for (int j = 0; j < 8; ++j) pk[j] = f2b(Lt[c0 + j][p] * SQRT_L2E);
        *(short8*)&theta_bf[((size_t)n * HW + p0 + p) * CRED + c0] = *(short8*)pk;
    }

    const int i   = t & 63;
    const int pj0 = t >> 6;
    const float mu = mean[i];
    const float sc = rsqrtf(var[i] + EPSV) * gamma[i];
    const float bi = beta[i];

    float acc[16];
#pragma unroll
    for (int k = 0; k < 16; ++k) acc[k] = 0.f;
#pragma unroll
    for (int c = 0; c < NCH; ++c) {
        float wci = Wt[c][i];
#pragma unroll
        for (int k = 0; k < 16; ++k) acc[k] += wci * Lt[c][pj0 + 4 * k];
    }
    __syncthreads();   // all reads of Wt done before reuse

#pragma unroll
    for (int k = 0; k < 16; ++k) {
        float y = (acc[k] - mu) * sc + bi;
        y = fminf(fmaxf(y, 0.f), 6.f);
        Wt[i][pj0 + 4 * k] = y;        // transpose buffer [i][p]
    }
    __syncthreads();

    {
        const int ir = t >> 2, pc = (t & 3) * 16;
        unsigned short pk[16];
#pragma unroll
        for (int j = 0; j < 16; ++j) pk[j] = f2b(Wt[ir][pc + j]);
        unsigned short* dst = &Gbt[((size_t)n * NCH + ir) * HW + p0 + pc];
        *(short8*)&dst[0] = *(short8*)&pk[0];
        *(short8*)&dst[8] = *(short8*)&pk[8];
    }
}

// ---- K2s (MFMA, no LDS): zpart[psp][n][q] = sum_{p in split} 2^(S'[q,p]) -------
// r14-verified.
__global__ __launch_bounds__(256) void k2s_stats(
    const unsigned short* __restrict__ theta_bf, float* __restrict__ zpart)
{
    const int t = threadIdx.x, w = t >> 6, lane = t & 63;
    const int lo = lane & 15, hi = lane >> 4;
    const int n = blockIdx.z, psp = blockIdx.y;
    const int q0 = blockIdx.x * 64;

    const unsigned short* thn = theta_bf + (size_t)n * HW * CRED;

    const short8 afrag = *(const short8*)&thn[(q0 + w * 16 + lo) * CRED + hi * 8];

    float z[4] = {0.f, 0.f, 0.f, 0.f};

    short8 bf[4];
    {
        const int p0 = psp * 448;
#pragma unroll
        for (int ss = 0; ss < 4; ++ss)
            bf[ss] = *(const short8*)&thn[(p0 + ss * 16 + lo) * CRED + hi * 8];
    }

    for (int pt = 0; pt < 7; ++pt) {
        // prefetch pt+1 fragments (clamped: pt=6 redundantly reloads pt=6, L1-hit)
        const int pn = psp * 448 + ((pt < 6) ? (pt + 1) * 64 : 6 * 64);
        short8 nf[4];
#pragma unroll
        for (int ss = 0; ss < 4; ++ss)
            nf[ss] = *(const short8*)&thn[(pn + ss * 16 + lo) * CRED + hi * 8];

#pragma unroll
        for (int ss = 0; ss < 4; ++ss) {
            f32x4 zero = {0.f, 0.f, 0.f, 0.f};
            f32x4 d = MFMA_B16(afrag, bf[ss], zero, 0, 0, 0);
#pragma unroll
            for (int r = 0; r < 4; ++r) z[r] += ex2(d[r]);
        }

#pragma unroll
        for (int ss = 0; ss < 4; ++ss) bf[ss] = nf[ss];
    }

#pragma unroll
    for (int r = 0; r < 4; ++r) {
        float v = z[r];
        v += __shfl_xor(v, 1, 64);
        v += __shfl_xor(v, 2, 64);
        v += __shfl_xor(v, 4, 64);
        v += __shfl_xor(v, 8, 64);
        z[r] = v;
    }
    if (lo == 0) {
        f32x4 st = {z[0], z[1], z[2], z[3]};
        *(f32x4*)&zpart[((size_t)psp * NB + n) * HW + q0 + w * 16 + hi * 4] = st;
    }
}

// ---- K2c: crow[n][q] = log2(log2 e) - log2(sum_psp zpart) ----------------------
__global__ __launch_bounds__(256) void k2c_combine(
    const float* __restrict__ zpart, float* __restrict__ crow)
{
    const int idx = blockIdx.x * 256 + threadIdx.x;
    float s = 0.f;
#pragma unroll
    for (int ps = 0; ps < QS2; ++ps) s += zpart[(size_t)ps * NB * HW + idx];
    crow[idx] = LOG2_L2E - __log2f(s);
}

// ---- K3f (MFMA): d = S' + crow (C-op); E = 2^(2^d); PV over q-slice ------------
// EXACT r10/r11/r14-verified kernel (passed 4x, 48.5 us). FROZEN.
__global__ __launch_bounds__(256) void k3f_fused(
    const unsigned short* __restrict__ theta_bf,
    const unsigned short* __restrict__ Gbt,
    const float* __restrict__ crow,
    half_t* __restrict__ Part, float* __restrict__ Zpart)
{
    __shared__ unsigned short Glt[64][76];   // G^T [i][q], pad 76
    __shared__ unsigned short El[64][76];    // E   [p][q] (wave-private rows)

    const int t = threadIdx.x, w = t >> 6, lane = t & 63;
    const int lo = lane & 15, hi = lane >> 4;
    const int n = blockIdx.z, qsp = blockIdx.y;
    const int pblk = blockIdx.x * 64;
    const int pw = w * 16;

    const unsigned short* thn = theta_bf + (size_t)n * HW * CRED;
    const float* crn = crow + (size_t)n * HW;

    // block-invariant theta_p fragment, direct from global
    const short8 bp = *(const short8*)&thn[(pblk + pw + lo) * CRED + hi * 8];

    f32x4 acc[4];
#pragma unroll
    for (int it = 0; it < 4; ++it) acc[it] = (f32x4){0.f, 0.f, 0.f, 0.f};
    float zl = 0.f;

    for (int tile = 0; tile < 7; ++tile) {
        const int qb = qsp * 448 + tile * 64;
        __syncthreads();
        // stage G^T tile: pure bf16 row copy
        {
            const int ir = t >> 2, qoff = (t & 3) * 16;
            const unsigned short* src = &Gbt[((size_t)n * NCH + ir) * HW + qb + qoff];
            *(short8*)&Glt[ir][qoff]     = *(const short8*)&src[0];
            *(short8*)&Glt[ir][qoff + 8] = *(const short8*)&src[8];
        }
        // issue this tile's aq/crow loads here: they complete by the barrier's
        // implicit vmcnt(0) drain, making the S phase pure compute.
        short8 aqr[4];
        f32x4  cvr[4];
#pragma unroll
        for (int s = 0; s < 4; ++s) {
            aqr[s] = *(const short8*)&thn[(qb + s * 16 + lo) * CRED + hi * 8];
            cvr[s] = *(const f32x4*)&crn[qb + s * 16 + hi * 4];
        }
        __syncthreads();

        // S phase: 4 q-subtiles; E rows -> El[p][q]
#pragma unroll
        for (int s = 0; s < 4; ++s) {
            f32x4 d = MFMA_B16(aqr[s], bp, cvr[s], 0, 0, 0);
            float e0 = ex2(ex2(d[0]));
            float e1 = ex2(ex2(d[1]));
            float e2 = ex2(ex2(d[2]));
            float e3 = ex2(ex2(d[3]));
            zl += (e0 + e1) + (e2 + e3);
            unsigned* dst = (unsigned*)&El[pw + lo][s * 16 + hi * 4];
            dst[0] = cvtpk(e0, e1);
            dst[1] = cvtpk(e2, e3);
        }

        // PV phase: acc[it] (D[p][i]) += El[p][q] * Glt[i][q]
#pragma unroll
        for (int ks = 0; ks < 2; ++ks) {
            const short8 ae = *(const short8*)&El[pw + lo][ks * 32 + hi * 8];
#pragma unroll
            for (int it = 0; it < 4; ++it) {
                const short8 bg = *(const short8*)&Glt[it * 16 + lo][ks * 32 + hi * 8];
                acc[it] = MFMA_B16(ae, bg, acc[it], 0, 0, 0);
            }
        }
    }

    // Part[n,qsp][i][p] fp16
    half_t* Pn = Part + ((size_t)n * QS2 + qsp) * (size_t)NCH * HW;
#pragma unroll
    for (int it = 0; it < 4; ++it) {
        half4v h;
        h[0] = (half_t)acc[it][0]; h[1] = (half_t)acc[it][1];
        h[2] = (half_t)acc[it][2]; h[3] = (half_t)acc[it][3];
        *(half4v*)&Pn[(size_t)(it * 16 + lo) * HW + pblk + pw + hi * 4] = h;
    }
    zl += __shfl_xor(zl, 16, 64);
    zl += __shfl_xor(zl, 32, 64);
    if (lane < 16)
        Zpart[((size_t)n * QS2 + qsp) * HW + pblk + pw + lane] = zl;
}

// ---- K34: fused (reduce q-slices + Z-normalize) + depthwise 3x3 + BN2 + res ----
// r14-verified structure, now fully vectorized: half4v Part reads (8B), f32x4
// Zpart/l reads, f32x4 op/out writes. 4x fewer memory instructions.
__global__ __launch_bounds__(256) void k34_reduce_dw(
    const half_t* __restrict__ Part, const float* __restrict__ Zpart,
    const float* __restrict__ l, const float* __restrict__ wdw,
    const float* __restrict__ gamma, const float* __restrict__ beta,
    const float* __restrict__ mean, const float* __restrict__ var,
    float* __restrict__ out)
{
    __shared__ float op[4][16][56];   // normalized OutPre, halo rows
    __shared__ float zsh[16][56];     // 1/Z for halo rows
    __shared__ float wsh[36];         // dw weights for the 4 channels

    const int t    = threadIdx.x;
    const int band = blockIdx.x;            // 0..3, y0 = band*14
    const int i0   = blockIdx.y * 4;        // channel group
    const int n    = blockIdx.z;
    const int y0   = band * 14;

    if (t < 36) wsh[t] = wdw[i0 * 9 + t];

    // 1/Z for halo rows [y0-1, y0+14], 4 x at a time (16*14 = 224 quads)
    if (t < 16 * 14) {
        const int row = t / 14, xq = (t % 14) * 4;
        const int yy = y0 - 1 + row;
        if (yy >= 0 && yy < 56) {
            const int p = yy * 56 + xq;
            f32x4 z = {0.f, 0.f, 0.f, 0.f};
#pragma unroll
            for (int qs = 0; qs < QS2; ++qs)
                z += *(const f32x4*)&Zpart[((size_t)n * QS2 + qs) * HW + p];
            f32x4 zi = {1.f / z[0], 1.f / z[1], 1.f / z[2], 1.f / z[3]};
            *(f32x4*)&zsh[row][xq] = zi;
        }
    }
    __syncthreads();

    // reduce Part over 7 slices (half4v), normalize -> op[c][row][xq..xq+3]
    for (int idx = t; idx < 4 * 16 * 14; idx += 256) {
        const int c = idx / (16 * 14), rem = idx % (16 * 14);
        const int row = rem / 14, xq = (rem % 14) * 4;
        const int yy = y0 - 1 + row;
        if (yy >= 0 && yy < 56) {
            const int p = yy * 56 + xq;
            const int i = i0 + c;
            f32x4 s = {0.f, 0.f, 0.f, 0.f};
#pragma unroll
            for (int qs = 0; qs < QS2; ++qs) {
                half4v h = *(const half4v*)
                    &Part[(((size_t)n * QS2 + qs) * NCH + i) * HW + p];
                s[0] += (float)h[0]; s[1] += (float)h[1];
                s[2] += (float)h[2]; s[3] += (float)h[3];
            }
            const f32x4 zi = *(const f32x4*)&zsh[row][xq];
            f32x4 o = {s[0] * zi[0], s[1] * zi[1], s[2] * zi[2], s[3] * zi[3]};
            *(f32x4*)&op[c][row][xq] = o;
        }
    }
    __syncthreads();

    // stencil + BN2 + residual, 4 x per thread (4*14*14 = 784 quads)
    for (int idx = t; idx < 4 * 14 * 14; idx += 256) {
        const int c = idx / (14 * 14), rem = idx % (14 * 14);
        const int y = y0 + rem / 14, xq = (rem % 14) * 4;
        const int i = i0 + c;

        float res[4];
#pragma unroll
        for (int j = 0; j < 4; ++j) {
            const int x = xq + j;
            float acc = 0.f;
#pragma unroll
            for (int dy = -1; dy <= 1; ++dy) {
                const int yy = y + dy;
                if (yy < 0 || yy >= 56) continue;
                const int ly = yy - (y0 - 1);
#pragma unroll
                for (int dx = -1; dx <= 1; ++dx) {
                    const int xx = x + dx;
                    if (xx < 0 || xx >= 56) continue;
                    acc += wsh[c * 9 + (dy + 1) * 3 + (dx + 1)] * op[c][ly][xx];
                }
            }
            res[j] = acc;
        }
        const float sc = rsqrtf(var[i] + EPSV) * gamma[i];
        const float mu = mean[i], bi = beta[i];
        const size_t e = ((size_t)n * NCH + i) * HW + y * 56 + xq;
        const f32x4 lv = *(const f32x4*)&l[e];
        f32x4 o = {(res[0] - mu) * sc + bi + lv[0],
                   (res[1] - mu) * sc + bi + lv[1],
                   (res[2] - mu) * sc + bi + lv[2],
                   (res[3] - mu) * sc + bi + lv[3]};
        *(f32x4*)&out[e] = o;
    }
}

// -------------------------------------------------------------------------------
extern "C" void kernel_launch(void* const* d_in, const int* in_sizes, int n_in,
                              void* d_out, int out_size, void* d_ws, size_t ws_size,
                              hipStream_t stream)
{
    const float* l      = (const float*)d_in[0];
    const float* w_in   = (const float*)d_in[1];
    const float* gamma1 = (const float*)d_in[2];
    const float* beta1  = (const float*)d_in[3];
    const float* mean1  = (const float*)d_in[4];
    const float* var1   = (const float*)d_in[5];
    const float* w_dw   = (const float*)d_in[6];
    const float* gamma2 = (const float*)d_in[7];
    const float* beta2  = (const float*)d_in[8];
    const float* mean2  = (const float*)d_in[9];
    const float* var2   = (const float*)d_in[10];
    float* out = (float*)d_out;

    char* ws = (char*)d_ws;
    const size_t szTheta = (size_t)NB * HW * CRED * 2;        // 1.6 MB
    const size_t szGbt   = (size_t)NB * NCH * HW * 2;         // 3.2 MB
    const size_t szCrow  = (size_t)NB * HW * 4;               // 100 KB
    const size_t szZpt   = (size_t)QS2 * NB * HW * 4;         // 0.7 MB
    const size_t szZp    = (size_t)NB * QS2 * HW * 4;         // 0.7 MB

    unsigned short* theta_bf = (unsigned short*)ws;
    unsigned short* Gbt      = (unsigned short*)(ws + szTheta);
    float* crow   = (float*)(ws + szTheta + szGbt);
    float* zpart  = (float*)(ws + szTheta + szGbt + szCrow);
    float* Zp     = (float*)(ws + szTheta + szGbt + szCrow + szZpt);
    half_t* Part  = (half_t*)(ws + szTheta + szGbt + szCrow + szZpt + szZp);
    (void)ws_size;

    k1_conv1x1<<<dim3(HW / 64, NB), 256, 0, stream>>>(
        l, w_in, gamma1, beta1, mean1, var1, theta_bf, Gbt);

    k2s_stats<<<dim3(HW / 64, QS2, NB), 256, 0, stream>>>(theta_bf, zpart);

    k2c_combine<<<dim3((NB * HW) / 256), 256, 0, stream>>>(zpart, crow);

    k3f_fused<<<dim3(HW / 64, QS2, NB), 256, 0, stream>>>(
        theta_bf, Gbt, crow, Part, Zp);

    k34_reduce_dw<<<dim3(4, NCH / 4, NB), 256, 0, stream>>>(
        Part, Zp, l, w_dw, gamma2, beta2, mean2, var2, out);
}

// Round 17
// 95.838 us; speedup vs baseline: 1.2657x; 1.0019x over previous
//
#include <hip/hip_runtime.h>

#define HW   3136
#define NCH  64
#define CRED 32
#define NB   8
#define EPSV 1e-5f
#define QS2  7

// sqrt(log2(e)) — both theta operands scaled => S' = S * log2(e)
#define SQRT_L2E 1.2011224087f
// log2(log2(e))
#define LOG2_L2E 0.5287663729f

typedef __attribute__((ext_vector_type(8))) short short8;
typedef __attribute__((ext_vector_type(4))) float f32x4;
typedef __attribute__((ext_vector_type(2))) float f32x2;
typedef _Float16 half_t;
typedef __attribute__((ext_vector_type(2))) _Float16 half2v;
typedef __attribute__((ext_vector_type(4))) _Float16 half4v;

#define MFMA_B16 __builtin_amdgcn_mfma_f32_16x16x32_bf16

__device__ __forceinline__ unsigned short f2b(float x) {
    union { float f; unsigned u; } v; v.f = x;
    unsigned r = v.u + 0x7fff + ((v.u >> 16) & 1);
    return (unsigned short)(r >> 16);
}

// raw v_exp_f32: 2^x
__device__ __forceinline__ float ex2(float x) {
#if __has_builtin(__builtin_amdgcn_exp2f)
    return __builtin_amdgcn_exp2f(x);
#else
    float r;
    asm volatile("v_exp_f32 %0, %1" : "=v"(r) : "v"(x));
    return r;
#endif
}

// pack two f32 -> bf16x2 in one instruction
__device__ __forceinline__ unsigned cvtpk(float a, float b) {
    unsigned r;
    asm("v_cvt_pk_bf16_f32 %0, %1, %2" : "=v"(r) : "v"(a), "v"(b));
    return r;
}

// async global->LDS DMA, 16B per lane; dst = wave-uniform base + lane*16
__device__ __forceinline__ void gload_lds16(const void* g, void* l) {
    __builtin_amdgcn_global_load_lds(
        (const __attribute__((address_space(1))) void*)g,
        (__attribute__((address_space(3))) void*)l, 16, 0, 0);
}

// ---- K1: conv1x1 + BN1 + ReLU6 -> Gbt[n][i][p] bf16; theta_bf[n][p][c] scaled --
__global__ __launch_bounds__(256) void k1_conv1x1(
    const float* __restrict__ l, const float* __restrict__ w,
    const float* __restrict__ gamma, const float* __restrict__ beta,
    const float* __restrict__ mean, const float* __restrict__ var,
    unsigned short* __restrict__ theta_bf, unsigned short* __restrict__ Gbt)
{
    __shared__ float Wt[NCH][65];   // Wt[c][i]; reused as G-transpose [i][p]
    __shared__ float Lt[NCH][65];   // Lt[c][j]
    const int t  = threadIdx.x;
    const int n  = blockIdx.y;
    const int p0 = blockIdx.x * 64;

    for (int idx = t; idx < NCH * 64; idx += 256) {
        int c = idx >> 6, j = idx & 63;
        Wt[c][j] = w[j * NCH + c];
        Lt[c][j] = l[((size_t)n * NCH + c) * HW + p0 + j];
    }
    __syncthreads();

    // emit theta_bf[n][p0+p][c0..c0+7], pre-scaled by sqrt(log2 e)
    {
        const int p = t >> 2, c0 = (t & 3) * 8;
        unsigned short pk[8];
#pragma unroll
        for (int j = 0; j < 8; ++j) pk[j] = f2b(Lt[c0 + j][p] * SQRT_L2E);
        *(short8*)&theta_bf[((size_t)n * HW + p0 + p) * CRED + c0] = *(short8*)pk;
    }

    const int i   = t & 63;
    const int pj0 = t >> 6;
    const float mu = mean[i];
    const float sc = rsqrtf(var[i] + EPSV) * gamma[i];
    const float bi = beta[i];

    float acc[16];
#pragma unroll
    for (int k = 0; k < 16; ++k) acc[k] = 0.f;
#pragma unroll
    for (int c = 0; c < NCH; ++c) {
        float wci = Wt[c][i];
#pragma unroll
        for (int k = 0; k < 16; ++k) acc[k] += wci * Lt[c][pj0 + 4 * k];
    }
    __syncthreads();   // all reads of Wt done before reuse

#pragma unroll
    for (int k = 0; k < 16; ++k) {
        float y = (acc[k] - mu) * sc + bi;
        y = fminf(fmaxf(y, 0.f), 6.f);
        Wt[i][pj0 + 4 * k] = y;        // transpose buffer [i][p]
    }
    __syncthreads();

    {
        const int ir = t >> 2, pc = (t & 3) * 16;
        unsigned short pk[16];
#pragma unroll
        for (int j = 0; j < 16; ++j) pk[j] = f2b(Wt[ir][pc + j]);
        unsigned short* dst = &Gbt[((size_t)n * NCH + ir) * HW + p0 + pc];
        *(short8*)&dst[0] = *(short8*)&pk[0];
        *(short8*)&dst[8] = *(short8*)&pk[8];
    }
}

// ---- K2s (MFMA, no LDS): zpart[psp][n][q] = sum_{p in split} 2^(S'[q,p]) -------
// r14-verified.
__global__ __launch_bounds__(256) void k2s_stats(
    const unsigned short* __restrict__ theta_bf, float* __restrict__ zpart)
{
    const int t = threadIdx.x, w = t >> 6, lane = t & 63;
    const int lo = lane & 15, hi = lane >> 4;
    const int n = blockIdx.z, psp = blockIdx.y;
    const int q0 = blockIdx.x * 64;

    const unsigned short* thn = theta_bf + (size_t)n * HW * CRED;

    const short8 afrag = *(const short8*)&thn[(q0 + w * 16 + lo) * CRED + hi * 8];

    float z[4] = {0.f, 0.f, 0.f, 0.f};

    short8 bf[4];
    {
        const int p0 = psp * 448;
#pragma unroll
        for (int ss = 0; ss < 4; ++ss)
            bf[ss] = *(const short8*)&thn[(p0 + ss * 16 + lo) * CRED + hi * 8];
    }

    for (int pt = 0; pt < 7; ++pt) {
        // prefetch pt+1 fragments (clamped: pt=6 redundantly reloads pt=6, L1-hit)
        const int pn = psp * 448 + ((pt < 6) ? (pt + 1) * 64 : 6 * 64);
        short8 nf[4];
#pragma unroll
        for (int ss = 0; ss < 4; ++ss)
            nf[ss] = *(const short8*)&thn[(pn + ss * 16 + lo) * CRED + hi * 8];

#pragma unroll
        for (int ss = 0; ss < 4; ++ss) {
            f32x4 zero = {0.f, 0.f, 0.f, 0.f};
            f32x4 d = MFMA_B16(afrag, bf[ss], zero, 0, 0, 0);
#pragma unroll
            for (int r = 0; r < 4; ++r) z[r] += ex2(d[r]);
        }

#pragma unroll
        for (int ss = 0; ss < 4; ++ss) bf[ss] = nf[ss];
    }

#pragma unroll
    for (int r = 0; r < 4; ++r) {
        float v = z[r];
        v += __shfl_xor(v, 1, 64);
        v += __shfl_xor(v, 2, 64);
        v += __shfl_xor(v, 4, 64);
        v += __shfl_xor(v, 8, 64);
        z[r] = v;
    }
    if (lo == 0) {
        f32x4 st = {z[0], z[1], z[2], z[3]};
        *(f32x4*)&zpart[((size_t)psp * NB + n) * HW + q0 + w * 16 + hi * 4] = st;
    }
}

// ---- K2c: crow[n][q] = log2(log2 e) - log2(sum_psp zpart) ----------------------
__global__ __launch_bounds__(256) void k2c_combine(
    const float* __restrict__ zpart, float* __restrict__ crow)
{
    const int idx = blockIdx.x * 256 + threadIdx.x;
    float s = 0.f;
#pragma unroll
    for (int ps = 0; ps < QS2; ++ps) s += zpart[(size_t)ps * NB * HW + idx];
    crow[idx] = LOG2_L2E - __log2f(s);
}

// ---- K3f (MFMA): d = S' + crow (C-op); E = 2^(2^d); PV over q-slice ------------
// r10/r11/r14/r16-verified sync skeleton (2 barriers/tile). Staging change only:
// Glt is filled via async global_load_lds (16B/lane, wave-uniform dest base) —
// no VGPR round trip, no exposed waitcnt; the 2nd barrier's implicit vmcnt(0)
// drain guarantees completion (same semantics as before). Because gload_lds
// writes linearly, Glt is linear [64][64] with XOR-swizzled SOURCE (chunk j of
// row r receives global chunk j^(r&7)) and the matching XOR on the bg read
// (rule #21: both-sides-or-neither). Read banks: 8 distinct 16B slots per 8
// lanes -> conflict-free (2-way aliasing is free). El path untouched.
__global__ __launch_bounds__(256) void k3f_fused(
    const unsigned short* __restrict__ theta_bf,
    const unsigned short* __restrict__ Gbt,
    const float* __restrict__ crow,
    half_t* __restrict__ Part, float* __restrict__ Zpart)
{
    __shared__ unsigned short Glt[64][64];   // G^T [i][q-chunks], linear, swizzled
    __shared__ unsigned short El[64][76];    // E   [p][q] (wave-private rows)

    const int t = threadIdx.x, w = t >> 6, lane = t & 63;
    const int lo = lane & 15, hi = lane >> 4;
    const int n = blockIdx.z, qsp = blockIdx.y;
    const int pblk = blockIdx.x * 64;
    const int pw = w * 16;

    const unsigned short* thn = theta_bf + (size_t)n * HW * CRED;
    const float* crn = crow + (size_t)n * HW;
    const unsigned short* gbn = Gbt + (size_t)n * NCH * HW;

    // block-invariant theta_p fragment, direct from global
    const short8 bp = *(const short8*)&thn[(pblk + pw + lo) * CRED + hi * 8];

    // chunk ids this lane DMAs (2 per lane, 512 total = 64 rows x 8 chunks)
    const int s0 = (w * 2 + 0) * 64 + lane;
    const int s1 = (w * 2 + 1) * 64 + lane;
    const int r0 = s0 >> 3, j0 = (s0 & 7) ^ (r0 & 7);
    const int r1 = s1 >> 3, j1 = (s1 & 7) ^ (r1 & 7);
    char* lbase = (char*)&Glt[0][0];

    f32x4 acc[4];
#pragma unroll
    for (int it = 0; it < 4; ++it) acc[it] = (f32x4){0.f, 0.f, 0.f, 0.f};
    float zl = 0.f;

    for (int tile = 0; tile < 7; ++tile) {
        const int qb = qsp * 448 + tile * 64;
        __syncthreads();
        // stage G^T tile: async DMA, swizzled source, linear LDS dest
        gload_lds16(&gbn[(size_t)r0 * HW + qb + j0 * 8],
                    lbase + (size_t)(w * 2 + 0) * 1024);
        gload_lds16(&gbn[(size_t)r1 * HW + qb + j1 * 8],
                    lbase + (size_t)(w * 2 + 1) * 1024);
        // issue this tile's aq/crow loads here: they (and the DMA) complete by
        // the barrier's implicit vmcnt(0) drain -> S phase is pure compute.
        short8 aqr[4];
        f32x4  cvr[4];
#pragma unroll
        for (int s = 0; s < 4; ++s) {
            aqr[s] = *(const short8*)&thn[(qb + s * 16 + lo) * CRED + hi * 8];
            cvr[s] = *(const f32x4*)&crn[qb + s * 16 + hi * 4];
        }
        __syncthreads();

        // S phase: 4 q-subtiles; E rows -> El[p][q]
#pragma unroll
        for (int s = 0; s < 4; ++s) {
            f32x4 d = MFMA_B16(aqr[s], bp, cvr[s], 0, 0, 0);
            float e0 = ex2(ex2(d[0]));
            float e1 = ex2(ex2(d[1]));
            float e2 = ex2(ex2(d[2]));
            float e3 = ex2(ex2(d[3]));
            zl += (e0 + e1) + (e2 + e3);
            unsigned* dst = (unsigned*)&El[pw + lo][s * 16 + hi * 4];
            dst[0] = cvtpk(e0, e1);
            dst[1] = cvtpk(e2, e3);
        }

        // PV phase: acc[it] (D[p][i]) += El[p][q] * Glt[i][q] (swizzled read)
        const unsigned short* gl = &Glt[0][0];
#pragma unroll
        for (int ks = 0; ks < 2; ++ks) {
            const short8 ae = *(const short8*)&El[pw + lo][ks * 32 + hi * 8];
#pragma unroll
            for (int it = 0; it < 4; ++it) {
                const int row = it * 16 + lo;
                const int cc  = (ks * 4 + hi) ^ (row & 7);
                const short8 bg = *(const short8*)&gl[row * 64 + cc * 8];
                acc[it] = MFMA_B16(ae, bg, acc[it], 0, 0, 0);
            }
        }
    }

    // Part[n,qsp][i][p] fp16
    half_t* Pn = Part + ((size_t)n * QS2 + qsp) * (size_t)NCH * HW;
#pragma unroll
    for (int it = 0; it < 4; ++it) {
        half4v h;
        h[0] = (half_t)acc[it][0]; h[1] = (half_t)acc[it][1];
        h[2] = (half_t)acc[it][2]; h[3] = (half_t)acc[it][3];
        *(half4v*)&Pn[(size_t)(it * 16 + lo) * HW + pblk + pw + hi * 4] = h;
    }
    zl += __shfl_xor(zl, 16, 64);
    zl += __shfl_xor(zl, 32, 64);
    if (lane < 16)
        Zpart[((size_t)n * QS2 + qsp) * HW + pblk + pw + lane] = zl;
}

// ---- K34: fused (reduce q-slices + Z-normalize) + depthwise 3x3 + BN2 + res ----
// r16-verified (vectorized).
__global__ __launch_bounds__(256) void k34_reduce_dw(
    const half_t* __restrict__ Part, const float* __restrict__ Zpart,
    const float* __restrict__ l, const float* __restrict__ wdw,
    const float* __restrict__ gamma, const float* __restrict__ beta,
    const float* __restrict__ mean, const float* __restrict__ var,
    float* __restrict__ out)
{
    __shared__ float op[4][16][56];   // normalized OutPre, halo rows
    __shared__ float zsh[16][56];     // 1/Z for halo rows
    __shared__ float wsh[36];         // dw weights for the 4 channels

    const int t    = threadIdx.x;
    const int band = blockIdx.x;            // 0..3, y0 = band*14
    const int i0   = blockIdx.y * 4;        // channel group
    const int n    = blockIdx.z;
    const int y0   = band * 14;

    if (t < 36) wsh[t] = wdw[i0 * 9 + t];

    // 1/Z for halo rows [y0-1, y0+14], 4 x at a time (16*14 = 224 quads)
    if (t < 16 * 14) {
        const int row = t / 14, xq = (t % 14) * 4;
        const int yy = y0 - 1 + row;
        if (yy >= 0 && yy < 56) {
            const int p = yy * 56 + xq;
            f32x4 z = {0.f, 0.f, 0.f, 0.f};
#pragma unroll
            for (int qs = 0; qs < QS2; ++qs)
                z += *(const f32x4*)&Zpart[((size_t)n * QS2 + qs) * HW + p];
            f32x4 zi = {1.f / z[0], 1.f / z[1], 1.f / z[2], 1.f / z[3]};
            *(f32x4*)&zsh[row][xq] = zi;
        }
    }
    __syncthreads();

    // reduce Part over 7 slices (half4v), normalize -> op[c][row][xq..xq+3]
    for (int idx = t; idx < 4 * 16 * 14; idx += 256) {
        const int c = idx / (16 * 14), rem = idx % (16 * 14);
        const int row = rem / 14, xq = (rem % 14) * 4;
        const int yy = y0 - 1 + row;
        if (yy >= 0 && yy < 56) {
            const int p = yy * 56 + xq;
            const int i = i0 + c;
            f32x4 s = {0.f, 0.f, 0.f, 0.f};
#pragma unroll
            for (int qs = 0; qs < QS2; ++qs) {
                half4v h = *(const half4v*)
                    &Part[(((size_t)n * QS2 + qs) * NCH + i) * HW + p];
                s[0] += (float)h[0]; s[1] += (float)h[1];
                s[2] += (float)h[2]; s[3] += (float)h[3];
            }
            const f32x4 zi = *(const f32x4*)&zsh[row][xq];
            f32x4 o = {s[0] * zi[0], s[1] * zi[1], s[2] * zi[2], s[3] * zi[3]};
            *(f32x4*)&op[c][row][xq] = o;
        }
    }
    __syncthreads();

    // stencil + BN2 + residual, 4 x per thread (4*14*14 = 784 quads)
    for (int idx = t; idx < 4 * 14 * 14; idx += 256) {
        const int c = idx / (14 * 14), rem = idx % (14 * 14);
        const int y = y0 + rem / 14, xq = (rem % 14) * 4;
        const int i = i0 + c;

        float res[4];
#pragma unroll
        for (int j = 0; j < 4; ++j) {
            const int x = xq + j;
            float acc = 0.f;
#pragma unroll
            for (int dy = -1; dy <= 1; ++dy) {
                const int yy = y + dy;
                if (yy < 0 || yy >= 56) continue;
                const int ly = yy - (y0 - 1);
#pragma unroll
                for (int dx = -1; dx <= 1; ++dx) {
                    const int xx = x + dx;
                    if (xx < 0 || xx >= 56) continue;
                    acc += wsh[c * 9 + (dy + 1) * 3 + (dx + 1)] * op[c][ly][xx];
                }
            }
            res[j] = acc;
        }
        const float sc = rsqrtf(var[i] + EPSV) * gamma[i];
        const float mu = mean[i], bi = beta[i];
        const size_t e = ((size_t)n * NCH + i) * HW + y * 56 + xq;
        const f32x4 lv = *(const f32x4*)&l[e];
        f32x4 o = {(res[0] - mu) * sc + bi + lv[0],
                   (res[1] - mu) * sc + bi + lv[1],
                   (res[2] - mu) * sc + bi + lv[2],
                   (res[3] - mu) * sc + bi + lv[3]};
        *(f32x4*)&out[e] = o;
    }
}

// -------------------------------------------------------------------------------
extern "C" void kernel_launch(void* const* d_in, const int* in_sizes, int n_in,
                              void* d_out, int out_size, void* d_ws, size_t ws_size,
                              hipStream_t stream)
{
    const float* l      = (const float*)d_in[0];
    const float* w_in   = (const float*)d_in[1];
    const float* gamma1 = (const float*)d_in[2];
    const float* beta1  = (const float*)d_in[3];
    const float* mean1  = (const float*)d_in[4];
    const float* var1   = (const float*)d_in[5];
    const float* w_dw   = (const float*)d_in[6];
    const float* gamma2 = (const float*)d_in[7];
    const float* beta2  = (const float*)d_in[8];
    const float* mean2  = (const float*)d_in[9];
    const float* var2   = (const float*)d_in[10];
    float* out = (float*)d_out;

    char* ws = (char*)d_ws;
    const size_t szTheta = (size_t)NB * HW * CRED * 2;        // 1.6 MB
    const size_t szGbt   = (size_t)NB * NCH * HW * 2;         // 3.2 MB
    const size_t szCrow  = (size_t)NB * HW * 4;               // 100 KB
    const size_t szZpt   = (size_t)QS2 * NB * HW * 4;         // 0.7 MB
    const size_t szZp    = (size_t)NB * QS2 * HW * 4;         // 0.7 MB

    unsigned short* theta_bf = (unsigned short*)ws;
    unsigned short* Gbt      = (unsigned short*)(ws + szTheta);
    float* crow   = (float*)(ws + szTheta + szGbt);
    float* zpart  = (float*)(ws + szTheta + szGbt + szCrow);
    float* Zp     = (float*)(ws + szTheta + szGbt + szCrow + szZpt);
    half_t* Part  = (half_t*)(ws + szTheta + szGbt + szCrow + szZpt + szZp);
    (void)ws_size;

    k1_conv1x1<<<dim3(HW / 64, NB), 256, 0, stream>>>(
        l, w_in, gamma1, beta1, mean1, var1, theta_bf, Gbt);

    k2s_stats<<<dim3(HW / 64, QS2, NB), 256, 0, stream>>>(theta_bf, zpart);

    k2c_combine<<<dim3((NB * HW) / 256), 256, 0, stream>>>(zpart, crow);

    k3f_fused<<<dim3(HW / 64, QS2, NB), 256, 0, stream>>>(
        theta_bf, Gbt, crow, Part, Zp);

    k34_reduce_dw<<<dim3(4, NCH / 4, NB), 256, 0, stream>>>(
        Part, Zp, l, w_dw, gamma2, beta2, mean2, var2, out);
}

// Round 18
// 91.880 us; speedup vs baseline: 1.3202x; 1.0431x over previous
//
#include <hip/hip_runtime.h>

#define HW   3136
#define NCH  64
#define CRED 32
#define NB   8
#define EPSV 1e-5f
#define QS2  7

// sqrt(log2(e)) — both theta operands scaled => S' = S * log2(e)
#define SQRT_L2E 1.2011224087f
// log2(log2(e))
#define LOG2_L2E 0.5287663729f

typedef __attribute__((ext_vector_type(8))) short short8;
typedef __attribute__((ext_vector_type(4))) float f32x4;
typedef __attribute__((ext_vector_type(2))) float f32x2;
typedef _Float16 half_t;
typedef __attribute__((ext_vector_type(2))) _Float16 half2v;
typedef __attribute__((ext_vector_type(4))) _Float16 half4v;

// may_alias variants for the El write/read pair (kills TBAA reorder license)
typedef short8 __attribute__((may_alias)) short8_ma;
typedef unsigned __attribute__((may_alias)) uint_ma;

#define MFMA_B16 __builtin_amdgcn_mfma_f32_16x16x32_bf16

__device__ __forceinline__ unsigned short f2b(float x) {
    union { float f; unsigned u; } v; v.f = x;
    unsigned r = v.u + 0x7fff + ((v.u >> 16) & 1);
    return (unsigned short)(r >> 16);
}

// raw v_exp_f32: 2^x
__device__ __forceinline__ float ex2(float x) {
#if __has_builtin(__builtin_amdgcn_exp2f)
    return __builtin_amdgcn_exp2f(x);
#else
    float r;
    asm volatile("v_exp_f32 %0, %1" : "=v"(r) : "v"(x));
    return r;
#endif
}

// pack two f32 -> bf16x2 in one instruction
__device__ __forceinline__ unsigned cvtpk(float a, float b) {
    unsigned r;
    asm("v_cvt_pk_bf16_f32 %0, %1, %2" : "=v"(r) : "v"(a), "v"(b));
    return r;
}

// async global->LDS DMA, 16B per lane; dst = wave-uniform base + lane*16
__device__ __forceinline__ void gload_lds16(const void* g, void* l) {
    __builtin_amdgcn_global_load_lds(
        (const __attribute__((address_space(1))) void*)g,
        (__attribute__((address_space(3))) void*)l, 16, 0, 0);
}

// ---- K1: conv1x1 + BN1 + ReLU6 -> Gbt[n][i][p] bf16; theta_bf[n][p][c] scaled --
__global__ __launch_bounds__(256) void k1_conv1x1(
    const float* __restrict__ l, const float* __restrict__ w,
    const float* __restrict__ gamma, const float* __restrict__ beta,
    const float* __restrict__ mean, const float* __restrict__ var,
    unsigned short* __restrict__ theta_bf, unsigned short* __restrict__ Gbt)
{
    __shared__ float Wt[NCH][65];   // Wt[c][i]; reused as G-transpose [i][p]
    __shared__ float Lt[NCH][65];   // Lt[c][j]
    const int t  = threadIdx.x;
    const int n  = blockIdx.y;
    const int p0 = blockIdx.x * 64;

    for (int idx = t; idx < NCH * 64; idx += 256) {
        int c = idx >> 6, j = idx & 63;
        Wt[c][j] = w[j * NCH + c];
        Lt[c][j] = l[((size_t)n * NCH + c) * HW + p0 + j];
    }
    __syncthreads();

    // emit theta_bf[n][p0+p][c0..c0+7], pre-scaled by sqrt(log2 e)
    {
        const int p = t >> 2, c0 = (t & 3) * 8;
        unsigned short pk[8];
#pragma unroll
        for (int j = 0; j < 8; ++j) pk[j] = f2b(Lt[c0 + j][p] * SQRT_L2E);
        *(short8*)&theta_bf[((size_t)n * HW + p0 + p) * CRED + c0] = *(short8*)pk;
    }

    const int i   = t & 63;
    const int pj0 = t >> 6;
    const float mu = mean[i];
    const float sc = rsqrtf(var[i] + EPSV) * gamma[i];
    const float bi = beta[i];

    float acc[16];
#pragma unroll
    for (int k = 0; k < 16; ++k) acc[k] = 0.f;
#pragma unroll
    for (int c = 0; c < NCH; ++c) {
        float wci = Wt[c][i];
#pragma unroll
        for (int k = 0; k < 16; ++k) acc[k] += wci * Lt[c][pj0 + 4 * k];
    }
    __syncthreads();   // all reads of Wt done before reuse

#pragma unroll
    for (int k = 0; k < 16; ++k) {
        float y = (acc[k] - mu) * sc + bi;
        y = fminf(fmaxf(y, 0.f), 6.f);
        Wt[i][pj0 + 4 * k] = y;        // transpose buffer [i][p]
    }
    __syncthreads();

    {
        const int ir = t >> 2, pc = (t & 3) * 16;
        unsigned short pk[16];
#pragma unroll
        for (int j = 0; j < 16; ++j) pk[j] = f2b(Wt[ir][pc + j]);
        unsigned short* dst = &Gbt[((size_t)n * NCH + ir) * HW + p0 + pc];
        *(short8*)&dst[0] = *(short8*)&pk[0];
        *(short8*)&dst[8] = *(short8*)&pk[8];
    }
}

// ---- K2s (MFMA, no LDS): zpart[psp][n][q] = sum_{p in split} 2^(S'[q,p]) -------
// r14-verified.
__global__ __launch_bounds__(256) void k2s_stats(
    const unsigned short* __restrict__ theta_bf, float* __restrict__ zpart)
{
    const int t = threadIdx.x, w = t >> 6, lane = t & 63;
    const int lo = lane & 15, hi = lane >> 4;
    const int n = blockIdx.z, psp = blockIdx.y;
    const int q0 = blockIdx.x * 64;

    const unsigned short* thn = theta_bf + (size_t)n * HW * CRED;

    const short8 afrag = *(const short8*)&thn[(q0 + w * 16 + lo) * CRED + hi * 8];

    float z[4] = {0.f, 0.f, 0.f, 0.f};

    short8 bf[4];
    {
        const int p0 = psp * 448;
#pragma unroll
        for (int ss = 0; ss < 4; ++ss)
            bf[ss] = *(const short8*)&thn[(p0 + ss * 16 + lo) * CRED + hi * 8];
    }

    for (int pt = 0; pt < 7; ++pt) {
        // prefetch pt+1 fragments (clamped: pt=6 redundantly reloads pt=6, L1-hit)
        const int pn = psp * 448 + ((pt < 6) ? (pt + 1) * 64 : 6 * 64);
        short8 nf[4];
#pragma unroll
        for (int ss = 0; ss < 4; ++ss)
            nf[ss] = *(const short8*)&thn[(pn + ss * 16 + lo) * CRED + hi * 8];

#pragma unroll
        for (int ss = 0; ss < 4; ++ss) {
            f32x4 zero = {0.f, 0.f, 0.f, 0.f};
            f32x4 d = MFMA_B16(afrag, bf[ss], zero, 0, 0, 0);
#pragma unroll
            for (int r = 0; r < 4; ++r) z[r] += ex2(d[r]);
        }

#pragma unroll
        for (int ss = 0; ss < 4; ++ss) bf[ss] = nf[ss];
    }

#pragma unroll
    for (int r = 0; r < 4; ++r) {
        float v = z[r];
        v += __shfl_xor(v, 1, 64);
        v += __shfl_xor(v, 2, 64);
        v += __shfl_xor(v, 4, 64);
        v += __shfl_xor(v, 8, 64);
        z[r] = v;
    }
    if (lo == 0) {
        f32x4 st = {z[0], z[1], z[2], z[3]};
        *(f32x4*)&zpart[((size_t)psp * NB + n) * HW + q0 + w * 16 + hi * 4] = st;
    }
}

// ---- K2c: crow[n][q] = log2(log2 e) - log2(sum_psp zpart) ----------------------
__global__ __launch_bounds__(256) void k2c_combine(
    const float* __restrict__ zpart, float* __restrict__ crow)
{
    const int idx = blockIdx.x * 256 + threadIdx.x;
    float s = 0.f;
#pragma unroll
    for (int ps = 0; ps < QS2; ++ps) s += zpart[(size_t)ps * NB * HW + idx];
    crow[idx] = LOG2_L2E - __log2f(s);
}

// S+PV for one p-group: same verified sequence as r10..r17, parameterized by
// (bp fragment, accumulator, z accumulator). El accesses via may_alias types.
#define S_PV_GRP(BP, ACC, ZL)                                                  \
    do {                                                                       \
        _Pragma("unroll")                                                      \
        for (int s = 0; s < 4; ++s) {                                          \
            f32x4 d = MFMA_B16(aqr[s], BP, cvr[s], 0, 0, 0);                   \
            float e0 = ex2(ex2(d[0]));                                         \
            float e1 = ex2(ex2(d[1]));                                         \
            float e2 = ex2(ex2(d[2]));                                         \
            float e3 = ex2(ex2(d[3]));                                         \
            ZL += (e0 + e1) + (e2 + e3);                                       \
            uint_ma* dst = (uint_ma*)&El[pw + lo][s * 16 + hi * 4];            \
            dst[0] = cvtpk(e0, e1);                                            \
            dst[1] = cvtpk(e2, e3);                                            \
        }                                                                      \
        _Pragma("unroll")                                                      \
        for (int ks = 0; ks < 2; ++ks) {                                       \
            const short8 ae =                                                  \
                *(const short8_ma*)&El[pw + lo][ks * 32 + hi * 8];             \
            _Pragma("unroll")                                                  \
            for (int it = 0; it < 4; ++it) {                                   \
                const int row = it * 16 + lo;                                  \
                const int cc  = (ks * 4 + hi) ^ (row & 7);                     \
                const short8 bg = *(const short8_ma*)&gl[row * 64 + cc * 8];   \
                ACC[it] = MFMA_B16(ae, bg, ACC[it], 0, 0, 0);                  \
            }                                                                  \
        }                                                                      \
    } while (0)

// ---- K3f (MFMA): TWO p-groups per block share G tile, aq/cvr, barriers --------
// Sync skeleton identical to r10..r17 (2 barriers/tile). Group B re-runs the
// verified S->PV sequence on the SAME El buffer: wave-private rows, same-wave
// DS ops execute in order; may_alias + asm fence pin the compiler ordering.
// Fixed per-tile costs (DMA, aq/cvr loads, barrier drains) amortized over 2x.
__global__ __launch_bounds__(256) void k3f_fused(
    const unsigned short* __restrict__ theta_bf,
    const unsigned short* __restrict__ Gbt,
    const float* __restrict__ crow,
    half_t* __restrict__ Part, float* __restrict__ Zpart)
{
    __shared__ unsigned short Glt[64][64];   // G^T, linear, src-swizzled
    __shared__ unsigned short El[64][76];    // E [p][q] (wave-private rows)

    const int t = threadIdx.x, w = t >> 6, lane = t & 63;
    const int lo = lane & 15, hi = lane >> 4;
    const int n = blockIdx.z, qsp = blockIdx.y;
    const int pblk = blockIdx.x * 128;
    const bool has2 = (pblk + 128 <= HW);
    const int pblk2 = has2 ? pblk + 64 : pblk;
    const int pw = w * 16;

    const unsigned short* thn = theta_bf + (size_t)n * HW * CRED;
    const float* crn = crow + (size_t)n * HW;
    const unsigned short* gbn = Gbt + (size_t)n * NCH * HW;

    // per-group block-invariant theta_p fragments
    const short8 bp0 = *(const short8*)&thn[(pblk  + pw + lo) * CRED + hi * 8];
    const short8 bp1 = *(const short8*)&thn[(pblk2 + pw + lo) * CRED + hi * 8];

    // chunk ids this lane DMAs (2 per lane, 512 total = 64 rows x 8 chunks)
    const int s0 = (w * 2 + 0) * 64 + lane;
    const int s1 = (w * 2 + 1) * 64 + lane;
    const int r0 = s0 >> 3, j0 = (s0 & 7) ^ (r0 & 7);
    const int r1 = s1 >> 3, j1 = (s1 & 7) ^ (r1 & 7);
    char* lbase = (char*)&Glt[0][0];
    const unsigned short* gl = &Glt[0][0];

    f32x4 accA[4], accB[4];
#pragma unroll
    for (int it = 0; it < 4; ++it) {
        accA[it] = (f32x4){0.f, 0.f, 0.f, 0.f};
        accB[it] = (f32x4){0.f, 0.f, 0.f, 0.f};
    }
    float zlA = 0.f, zlB = 0.f;

    for (int tile = 0; tile < 7; ++tile) {
        const int qb = qsp * 448 + tile * 64;
        __syncthreads();
        // stage G^T tile: async DMA, swizzled source, linear LDS dest
        gload_lds16(&gbn[(size_t)r0 * HW + qb + j0 * 8],
                    lbase + (size_t)(w * 2 + 0) * 1024);
        gload_lds16(&gbn[(size_t)r1 * HW + qb + j1 * 8],
                    lbase + (size_t)(w * 2 + 1) * 1024);
        // aq/crow loads (shared by BOTH p-groups) drain at the barrier below
        short8 aqr[4];
        f32x4  cvr[4];
#pragma unroll
        for (int s = 0; s < 4; ++s) {
            aqr[s] = *(const short8*)&thn[(qb + s * 16 + lo) * CRED + hi * 8];
            cvr[s] = *(const f32x4*)&crn[qb + s * 16 + hi * 4];
        }
        __syncthreads();

        S_PV_GRP(bp0, accA, zlA);
        if (has2) {
            __asm__ __volatile__("" ::: "memory");   // pin El A-reads before B-writes
            S_PV_GRP(bp1, accB, zlB);
        }
    }

    // Part[n,qsp][i][p] fp16 — group A at pblk, group B at pblk+64
    half_t* Pn = Part + ((size_t)n * QS2 + qsp) * (size_t)NCH * HW;
#pragma unroll
    for (int it = 0; it < 4; ++it) {
        half4v h;
        h[0] = (half_t)accA[it][0]; h[1] = (half_t)accA[it][1];
        h[2] = (half_t)accA[it][2]; h[3] = (half_t)accA[it][3];
        *(half4v*)&Pn[(size_t)(it * 16 + lo) * HW + pblk + pw + hi * 4] = h;
    }
    zlA += __shfl_xor(zlA, 16, 64);
    zlA += __shfl_xor(zlA, 32, 64);
    if (lane < 16)
        Zpart[((size_t)n * QS2 + qsp) * HW + pblk + pw + lane] = zlA;

    if (has2) {
#pragma unroll
        for (int it = 0; it < 4; ++it) {
            half4v h;
            h[0] = (half_t)accB[it][0]; h[1] = (half_t)accB[it][1];
            h[2] = (half_t)accB[it][2]; h[3] = (half_t)accB[it][3];
            *(half4v*)&Pn[(size_t)(it * 16 + lo) * HW + pblk + 64 + pw + hi * 4] = h;
        }
        zlB += __shfl_xor(zlB, 16, 64);
        zlB += __shfl_xor(zlB, 32, 64);
        if (lane < 16)
            Zpart[((size_t)n * QS2 + qsp) * HW + pblk + 64 + pw + lane] = zlB;
    }
}

// ---- K34: fused (reduce q-slices + Z-normalize) + depthwise 3x3 + BN2 + res ----
// r16-verified (vectorized).
__global__ __launch_bounds__(256) void k34_reduce_dw(
    const half_t* __restrict__ Part, const float* __restrict__ Zpart,
    const float* __restrict__ l, const float* __restrict__ wdw,
    const float* __restrict__ gamma, const float* __restrict__ beta,
    const float* __restrict__ mean, const float* __restrict__ var,
    float* __restrict__ out)
{
    __shared__ float op[4][16][56];   // normalized OutPre, halo rows
    __shared__ float zsh[16][56];     // 1/Z for halo rows
    __shared__ float wsh[36];         // dw weights for the 4 channels

    const int t    = threadIdx.x;
    const int band = blockIdx.x;            // 0..3, y0 = band*14
    const int i0   = blockIdx.y * 4;        // channel group
    const int n    = blockIdx.z;
    const int y0   = band * 14;

    if (t < 36) wsh[t] = wdw[i0 * 9 + t];

    // 1/Z for halo rows [y0-1, y0+14], 4 x at a time (16*14 = 224 quads)
    if (t < 16 * 14) {
        const int row = t / 14, xq = (t % 14) * 4;
        const int yy = y0 - 1 + row;
        if (yy >= 0 && yy < 56) {
            const int p = yy * 56 + xq;
            f32x4 z = {0.f, 0.f, 0.f, 0.f};
#pragma unroll
            for (int qs = 0; qs < QS2; ++qs)
                z += *(const f32x4*)&Zpart[((size_t)n * QS2 + qs) * HW + p];
            f32x4 zi = {1.f / z[0], 1.f / z[1], 1.f / z[2], 1.f / z[3]};
            *(f32x4*)&zsh[row][xq] = zi;
        }
    }
    __syncthreads();

    // reduce Part over 7 slices (half4v), normalize -> op[c][row][xq..xq+3]
    for (int idx = t; idx < 4 * 16 * 14; idx += 256) {
        const int c = idx / (16 * 14), rem = idx % (16 * 14);
        const int row = rem / 14, xq = (rem % 14) * 4;
        const int yy = y0 - 1 + row;
        if (yy >= 0 && yy < 56) {
            const int p = yy * 56 + xq;
            const int i = i0 + c;
            f32x4 s = {0.f, 0.f, 0.f, 0.f};
#pragma unroll
            for (int qs = 0; qs < QS2; ++qs) {
                half4v h = *(const half4v*)
                    &Part[(((size_t)n * QS2 + qs) * NCH + i) * HW + p];
                s[0] += (float)h[0]; s[1] += (float)h[1];
                s[2] += (float)h[2]; s[3] += (float)h[3];
            }
            const f32x4 zi = *(const f32x4*)&zsh[row][xq];
            f32x4 o = {s[0] * zi[0], s[1] * zi[1], s[2] * zi[2], s[3] * zi[3]};
            *(f32x4*)&op[c][row][xq] = o;
        }
    }
    __syncthreads();

    // stencil + BN2 + residual, 4 x per thread (4*14*14 = 784 quads)
    for (int idx = t; idx < 4 * 14 * 14; idx += 256) {
        const int c = idx / (14 * 14), rem = idx % (14 * 14);
        const int y = y0 + rem / 14, xq = (rem % 14) * 4;
        const int i = i0 + c;

        float res[4];
#pragma unroll
        for (int j = 0; j < 4; ++j) {
            const int x = xq + j;
            float acc = 0.f;
#pragma unroll
            for (int dy = -1; dy <= 1; ++dy) {
                const int yy = y + dy;
                if (yy < 0 || yy >= 56) continue;
                const int ly = yy - (y0 - 1);
#pragma unroll
                for (int dx = -1; dx <= 1; ++dx) {
                    const int xx = x + dx;
                    if (xx < 0 || xx >= 56) continue;
                    acc += wsh[c * 9 + (dy + 1) * 3 + (dx + 1)] * op[c][ly][xx];
                }
            }
            res[j] = acc;
        }
        const float sc = rsqrtf(var[i] + EPSV) * gamma[i];
        const float mu = mean[i], bi = beta[i];
        const size_t e = ((size_t)n * NCH + i) * HW + y * 56 + xq;
        const f32x4 lv = *(const f32x4*)&l[e];
        f32x4 o = {(res[0] - mu) * sc + bi + lv[0],
                   (res[1] - mu) * sc + bi + lv[1],
                   (res[2] - mu) * sc + bi + lv[2],
                   (res[3] - mu) * sc + bi + lv[3]};
        *(f32x4*)&out[e] = o;
    }
}

// -------------------------------------------------------------------------------
extern "C" void kernel_launch(void* const* d_in, const int* in_sizes, int n_in,
                              void* d_out, int out_size, void* d_ws, size_t ws_size,
                              hipStream_t stream)
{
    const float* l      = (const float*)d_in[0];
    const float* w_in   = (const float*)d_in[1];
    const float* gamma1 = (const float*)d_in[2];
    const float* beta1  = (const float*)d_in[3];
    const float* mean1  = (const float*)d_in[4];
    const float* var1   = (const float*)d_in[5];
    const float* w_dw   = (const float*)d_in[6];
    const float* gamma2 = (const float*)d_in[7];
    const float* beta2  = (const float*)d_in[8];
    const float* mean2  = (const float*)d_in[9];
    const float* var2   = (const float*)d_in[10];
    float* out = (float*)d_out;

    char* ws = (char*)d_ws;
    const size_t szTheta = (size_t)NB * HW * CRED * 2;        // 1.6 MB
    const size_t szGbt   = (size_t)NB * NCH * HW * 2;         // 3.2 MB
    const size_t szCrow  = (size_t)NB * HW * 4;               // 100 KB
    const size_t szZpt   = (size_t)QS2 * NB * HW * 4;         // 0.7 MB
    const size_t szZp    = (size_t)NB * QS2 * HW * 4;         // 0.7 MB

    unsigned short* theta_bf = (unsigned short*)ws;
    unsigned short* Gbt      = (unsigned short*)(ws + szTheta);
    float* crow   = (float*)(ws + szTheta + szGbt);
    float* zpart  = (float*)(ws + szTheta + szGbt + szCrow);
    float* Zp     = (float*)(ws + szTheta + szGbt + szCrow + szZpt);
    half_t* Part  = (half_t*)(ws + szTheta + szGbt + szCrow + szZpt + szZp);
    (void)ws_size;

    k1_conv1x1<<<dim3(HW / 64, NB), 256, 0, stream>>>(
        l, w_in, gamma1, beta1, mean1, var1, theta_bf, Gbt);

    k2s_stats<<<dim3(HW / 64, QS2, NB), 256, 0, stream>>>(theta_bf, zpart);

    k2c_combine<<<dim3((NB * HW) / 256), 256, 0, stream>>>(zpart, crow);

    k3f_fused<<<dim3((HW + 127) / 128, QS2, NB), 256, 0, stream>>>(
        theta_bf, Gbt, crow, Part, Zp);

    k34_reduce_dw<<<dim3(4, NCH / 4, NB), 256, 0, stream>>>(
        Part, Zp, l, w_dw, gamma2, beta2, mean2, var2, out);
}

// Round 19
// 86.093 us; speedup vs baseline: 1.4090x; 1.0672x over previous
//
#include <hip/hip_runtime.h>

#define HW   3136
#define NCH  64
#define CRED 32
#define NB   8
#define EPSV 1e-5f
#define QS2  7

// sqrt(log2(e)) — both theta operands scaled => S' = S * log2(e)
#define SQRT_L2E 1.2011224087f
// log2(log2(e))
#define LOG2_L2E 0.5287663729f

typedef __attribute__((ext_vector_type(8))) short short8;
typedef __attribute__((ext_vector_type(4))) float f32x4;
typedef __attribute__((ext_vector_type(2))) float f32x2;
typedef _Float16 half_t;
typedef __attribute__((ext_vector_type(2))) _Float16 half2v;
typedef __attribute__((ext_vector_type(4))) _Float16 half4v;

// may_alias variants for the El write/read pair (kills TBAA reorder license)
typedef short8 __attribute__((may_alias)) short8_ma;
typedef unsigned __attribute__((may_alias)) uint_ma;

#define MFMA_B16 __builtin_amdgcn_mfma_f32_16x16x32_bf16

__device__ __forceinline__ unsigned short f2b(float x) {
    union { float f; unsigned u; } v; v.f = x;
    unsigned r = v.u + 0x7fff + ((v.u >> 16) & 1);
    return (unsigned short)(r >> 16);
}

// raw v_exp_f32: 2^x
__device__ __forceinline__ float ex2(float x) {
#if __has_builtin(__builtin_amdgcn_exp2f)
    return __builtin_amdgcn_exp2f(x);
#else
    float r;
    asm volatile("v_exp_f32 %0, %1" : "=v"(r) : "v"(x));
    return r;
#endif
}

// pack two f32 -> bf16x2 in one instruction
__device__ __forceinline__ unsigned cvtpk(float a, float b) {
    unsigned r;
    asm("v_cvt_pk_bf16_f32 %0, %1, %2" : "=v"(r) : "v"(a), "v"(b));
    return r;
}

// async global->LDS DMA, 16B per lane; dst = wave-uniform base + lane*16
__device__ __forceinline__ void gload_lds16(const void* g, void* l) {
    __builtin_amdgcn_global_load_lds(
        (const __attribute__((address_space(1))) void*)g,
        (__attribute__((address_space(3))) void*)l, 16, 0, 0);
}

// ---- K1: conv1x1 + BN1 + ReLU6 -> Gbt[n][i][p] bf16; theta_bf[n][p][c] scaled --
__global__ __launch_bounds__(256) void k1_conv1x1(
    const float* __restrict__ l, const float* __restrict__ w,
    const float* __restrict__ gamma, const float* __restrict__ beta,
    const float* __restrict__ mean, const float* __restrict__ var,
    unsigned short* __restrict__ theta_bf, unsigned short* __restrict__ Gbt)
{
    __shared__ float Wt[NCH][65];   // Wt[c][i]; reused as G-transpose [i][p]
    __shared__ float Lt[NCH][65];   // Lt[c][j]
    const int t  = threadIdx.x;
    const int n  = blockIdx.y;
    const int p0 = blockIdx.x * 64;

    for (int idx = t; idx < NCH * 64; idx += 256) {
        int c = idx >> 6, j = idx & 63;
        Wt[c][j] = w[j * NCH + c];
        Lt[c][j] = l[((size_t)n * NCH + c) * HW + p0 + j];
    }
    __syncthreads();

    // emit theta_bf[n][p0+p][c0..c0+7], pre-scaled by sqrt(log2 e)
    {
        const int p = t >> 2, c0 = (t & 3) * 8;
        unsigned short pk[8];
#pragma unroll
        for (int j = 0; j < 8; ++j) pk[j] = f2b(Lt[c0 + j][p] * SQRT_L2E);
        *(short8*)&theta_bf[((size_t)n * HW + p0 + p) * CRED + c0] = *(short8*)pk;
    }

    const int i   = t & 63;
    const int pj0 = t >> 6;
    const float mu = mean[i];
    const float sc = rsqrtf(var[i] + EPSV) * gamma[i];
    const float bi = beta[i];

    float acc[16];
#pragma unroll
    for (int k = 0; k < 16; ++k) acc[k] = 0.f;
#pragma unroll
    for (int c = 0; c < NCH; ++c) {
        float wci = Wt[c][i];
#pragma unroll
        for (int k = 0; k < 16; ++k) acc[k] += wci * Lt[c][pj0 + 4 * k];
    }
    __syncthreads();   // all reads of Wt done before reuse

#pragma unroll
    for (int k = 0; k < 16; ++k) {
        float y = (acc[k] - mu) * sc + bi;
        y = fminf(fmaxf(y, 0.f), 6.f);
        Wt[i][pj0 + 4 * k] = y;        // transpose buffer [i][p]
    }
    __syncthreads();

    {
        const int ir = t >> 2, pc = (t & 3) * 16;
        unsigned short pk[16];
#pragma unroll
        for (int j = 0; j < 16; ++j) pk[j] = f2b(Wt[ir][pc + j]);
        unsigned short* dst = &Gbt[((size_t)n * NCH + ir) * HW + p0 + pc];
        *(short8*)&dst[0] = *(short8*)&pk[0];
        *(short8*)&dst[8] = *(short8*)&pk[8];
    }
}

// ---- K2s (MFMA, no LDS): TWO q-groups share the p-fragment stream --------------
// r14-verified structure x2: loads per MFMA halved, two independent MFMA->ex2
// chains for ILP. No LDS, no barriers (first-try-safe kernel class).
__global__ __launch_bounds__(256) void k2s_stats(
    const unsigned short* __restrict__ theta_bf, float* __restrict__ zpart)
{
    const int t = threadIdx.x, w = t >> 6, lane = t & 63;
    const int lo = lane & 15, hi = lane >> 4;
    const int n = blockIdx.z, psp = blockIdx.y;
    const int q0A = blockIdx.x * 128;
    const bool hasB = (q0A + 128 <= HW);
    const int q0B = hasB ? q0A + 64 : q0A;

    const unsigned short* thn = theta_bf + (size_t)n * HW * CRED;

    const short8 afA = *(const short8*)&thn[(q0A + w * 16 + lo) * CRED + hi * 8];
    const short8 afB = *(const short8*)&thn[(q0B + w * 16 + lo) * CRED + hi * 8];

    float zA[4] = {0.f, 0.f, 0.f, 0.f};
    float zB[4] = {0.f, 0.f, 0.f, 0.f};

    short8 bf[4];
    {
        const int p0 = psp * 448;
#pragma unroll
        for (int ss = 0; ss < 4; ++ss)
            bf[ss] = *(const short8*)&thn[(p0 + ss * 16 + lo) * CRED + hi * 8];
    }

    for (int pt = 0; pt < 7; ++pt) {
        // prefetch pt+1 fragments (clamped: pt=6 redundantly reloads pt=6, L1-hit)
        const int pn = psp * 448 + ((pt < 6) ? (pt + 1) * 64 : 6 * 64);
        short8 nf[4];
#pragma unroll
        for (int ss = 0; ss < 4; ++ss)
            nf[ss] = *(const short8*)&thn[(pn + ss * 16 + lo) * CRED + hi * 8];

#pragma unroll
        for (int ss = 0; ss < 4; ++ss) {
            f32x4 zero = {0.f, 0.f, 0.f, 0.f};
            f32x4 dA = MFMA_B16(afA, bf[ss], zero, 0, 0, 0);
            f32x4 dB = MFMA_B16(afB, bf[ss], zero, 0, 0, 0);
#pragma unroll
            for (int r = 0; r < 4; ++r) zA[r] += ex2(dA[r]);
#pragma unroll
            for (int r = 0; r < 4; ++r) zB[r] += ex2(dB[r]);
        }

#pragma unroll
        for (int ss = 0; ss < 4; ++ss) bf[ss] = nf[ss];
    }

#pragma unroll
    for (int r = 0; r < 4; ++r) {
        float vA = zA[r];
        vA += __shfl_xor(vA, 1, 64);
        vA += __shfl_xor(vA, 2, 64);
        vA += __shfl_xor(vA, 4, 64);
        vA += __shfl_xor(vA, 8, 64);
        zA[r] = vA;
        float vB = zB[r];
        vB += __shfl_xor(vB, 1, 64);
        vB += __shfl_xor(vB, 2, 64);
        vB += __shfl_xor(vB, 4, 64);
        vB += __shfl_xor(vB, 8, 64);
        zB[r] = vB;
    }
    if (lo == 0) {
        f32x4 stA = {zA[0], zA[1], zA[2], zA[3]};
        *(f32x4*)&zpart[((size_t)psp * NB + n) * HW + q0A + w * 16 + hi * 4] = stA;
        if (hasB) {
            f32x4 stB = {zB[0], zB[1], zB[2], zB[3]};
            *(f32x4*)&zpart[((size_t)psp * NB + n) * HW + q0B + w * 16 + hi * 4] = stB;
        }
    }
}

// ---- K2c: crow[n][q] = log2(log2 e) - log2(sum_psp zpart) ----------------------
__global__ __launch_bounds__(256) void k2c_combine(
    const float* __restrict__ zpart, float* __restrict__ crow)
{
    const int idx = blockIdx.x * 256 + threadIdx.x;
    float s = 0.f;
#pragma unroll
    for (int ps = 0; ps < QS2; ++ps) s += zpart[(size_t)ps * NB * HW + idx];
    crow[idx] = LOG2_L2E - __log2f(s);
}

// S+PV for one p-group: same verified sequence as r10..r18, parameterized by
// (bp fragment, accumulator, z accumulator). El accesses via may_alias types.
#define S_PV_GRP(BP, ACC, ZL)                                                  \
    do {                                                                       \
        _Pragma("unroll")                                                      \
        for (int s = 0; s < 4; ++s) {                                          \
            f32x4 d = MFMA_B16(aqr[s], BP, cvr[s], 0, 0, 0);                   \
            float e0 = ex2(ex2(d[0]));                                         \
            float e1 = ex2(ex2(d[1]));                                         \
            float e2 = ex2(ex2(d[2]));                                         \
            float e3 = ex2(ex2(d[3]));                                         \
            ZL += (e0 + e1) + (e2 + e3);                                       \
            uint_ma* dst = (uint_ma*)&El[pw + lo][s * 16 + hi * 4];            \
            dst[0] = cvtpk(e0, e1);                                            \
            dst[1] = cvtpk(e2, e3);                                            \
        }                                                                      \
        _Pragma("unroll")                                                      \
        for (int ks = 0; ks < 2; ++ks) {                                       \
            const short8 ae =                                                  \
                *(const short8_ma*)&El[pw + lo][ks * 32 + hi * 8];             \
            _Pragma("unroll")                                                  \
            for (int it = 0; it < 4; ++it) {                                   \
                const int row = it * 16 + lo;                                  \
                const int cc  = (ks * 4 + hi) ^ (row & 7);                     \
                const short8 bg = *(const short8_ma*)&gl[row * 64 + cc * 8];   \
                ACC[it] = MFMA_B16(ae, bg, ACC[it], 0, 0, 0);                  \
            }                                                                  \
        }                                                                      \
    } while (0)

// ---- K3f (MFMA): TWO p-groups per block share G tile, aq/cvr, barriers --------
// r18-verified. FROZEN.
__global__ __launch_bounds__(256) void k3f_fused(
    const unsigned short* __restrict__ theta_bf,
    const unsigned short* __restrict__ Gbt,
    const float* __restrict__ crow,
    half_t* __restrict__ Part, float* __restrict__ Zpart)
{
    __shared__ unsigned short Glt[64][64];   // G^T, linear, src-swizzled
    __shared__ unsigned short El[64][76];    // E [p][q] (wave-private rows)

    const int t = threadIdx.x, w = t >> 6, lane = t & 63;
    const int lo = lane & 15, hi = lane >> 4;
    const int n = blockIdx.z, qsp = blockIdx.y;
    const int pblk = blockIdx.x * 128;
    const bool has2 = (pblk + 128 <= HW);
    const int pblk2 = has2 ? pblk + 64 : pblk;
    const int pw = w * 16;

    const unsigned short* thn = theta_bf + (size_t)n * HW * CRED;
    const float* crn = crow + (size_t)n * HW;
    const unsigned short* gbn = Gbt + (size_t)n * NCH * HW;

    // per-group block-invariant theta_p fragments
    const short8 bp0 = *(const short8*)&thn[(pblk  + pw + lo) * CRED + hi * 8];
    const short8 bp1 = *(const short8*)&thn[(pblk2 + pw + lo) * CRED + hi * 8];

    // chunk ids this lane DMAs (2 per lane, 512 total = 64 rows x 8 chunks)
    const int s0 = (w * 2 + 0) * 64 + lane;
    const int s1 = (w * 2 + 1) * 64 + lane;
    const int r0 = s0 >> 3, j0 = (s0 & 7) ^ (r0 & 7);
    const int r1 = s1 >> 3, j1 = (s1 & 7) ^ (r1 & 7);
    char* lbase = (char*)&Glt[0][0];
    const unsigned short* gl = &Glt[0][0];

    f32x4 accA[4], accB[4];
#pragma unroll
    for (int it = 0; it < 4; ++it) {
        accA[it] = (f32x4){0.f, 0.f, 0.f, 0.f};
        accB[it] = (f32x4){0.f, 0.f, 0.f, 0.f};
    }
    float zlA = 0.f, zlB = 0.f;

    for (int tile = 0; tile < 7; ++tile) {
        const int qb = qsp * 448 + tile * 64;
        __syncthreads();
        // stage G^T tile: async DMA, swizzled source, linear LDS dest
        gload_lds16(&gbn[(size_t)r0 * HW + qb + j0 * 8],
                    lbase + (size_t)(w * 2 + 0) * 1024);
        gload_lds16(&gbn[(size_t)r1 * HW + qb + j1 * 8],
                    lbase + (size_t)(w * 2 + 1) * 1024);
        // aq/crow loads (shared by BOTH p-groups) drain at the barrier below
        short8 aqr[4];
        f32x4  cvr[4];
#pragma unroll
        for (int s = 0; s < 4; ++s) {
            aqr[s] = *(const short8*)&thn[(qb + s * 16 + lo) * CRED + hi * 8];
            cvr[s] = *(const f32x4*)&crn[qb + s * 16 + hi * 4];
        }
        __syncthreads();

        S_PV_GRP(bp0, accA, zlA);
        if (has2) {
            __asm__ __volatile__("" ::: "memory");   // pin El A-reads before B-writes
            S_PV_GRP(bp1, accB, zlB);
        }
    }

    // Part[n,qsp][i][p] fp16 — group A at pblk, group B at pblk+64
    half_t* Pn = Part + ((size_t)n * QS2 + qsp) * (size_t)NCH * HW;
#pragma unroll
    for (int it = 0; it < 4; ++it) {
        half4v h;
        h[0] = (half_t)accA[it][0]; h[1] = (half_t)accA[it][1];
        h[2] = (half_t)accA[it][2]; h[3] = (half_t)accA[it][3];
        *(half4v*)&Pn[(size_t)(it * 16 + lo) * HW + pblk + pw + hi * 4] = h;
    }
    zlA += __shfl_xor(zlA, 16, 64);
    zlA += __shfl_xor(zlA, 32, 64);
    if (lane < 16)
        Zpart[((size_t)n * QS2 + qsp) * HW + pblk + pw + lane] = zlA;

    if (has2) {
#pragma unroll
        for (int it = 0; it < 4; ++it) {
            half4v h;
            h[0] = (half_t)accB[it][0]; h[1] = (half_t)accB[it][1];
            h[2] = (half_t)accB[it][2]; h[3] = (half_t)accB[it][3];
            *(half4v*)&Pn[(size_t)(it * 16 + lo) * HW + pblk + 64 + pw + hi * 4] = h;
        }
        zlB += __shfl_xor(zlB, 16, 64);
        zlB += __shfl_xor(zlB, 32, 64);
        if (lane < 16)
            Zpart[((size_t)n * QS2 + qsp) * HW + pblk + 64 + pw + lane] = zlB;
    }
}

// ---- K34: fused (reduce q-slices + Z-normalize) + depthwise 3x3 + BN2 + res ----
// r16-verified (vectorized).
__global__ __launch_bounds__(256) void k34_reduce_dw(
    const half_t* __restrict__ Part, const float* __restrict__ Zpart,
    const float* __restrict__ l, const float* __restrict__ wdw,
    const float* __restrict__ gamma, const float* __restrict__ beta,
    const float* __restrict__ mean, const float* __restrict__ var,
    float* __restrict__ out)
{
    __shared__ float op[4][16][56];   // normalized OutPre, halo rows
    __shared__ float zsh[16][56];     // 1/Z for halo rows
    __shared__ float wsh[36];         // dw weights for the 4 channels

    const int t    = threadIdx.x;
    const int band = blockIdx.x;            // 0..3, y0 = band*14
    const int i0   = blockIdx.y * 4;        // channel group
    const int n    = blockIdx.z;
    const int y0   = band * 14;

    if (t < 36) wsh[t] = wdw[i0 * 9 + t];

    // 1/Z for halo rows [y0-1, y0+14], 4 x at a time (16*14 = 224 quads)
    if (t < 16 * 14) {
        const int row = t / 14, xq = (t % 14) * 4;
        const int yy = y0 - 1 + row;
        if (yy >= 0 && yy < 56) {
            const int p = yy * 56 + xq;
            f32x4 z = {0.f, 0.f, 0.f, 0.f};
#pragma unroll
            for (int qs = 0; qs < QS2; ++qs)
                z += *(const f32x4*)&Zpart[((size_t)n * QS2 + qs) * HW + p];
            f32x4 zi = {1.f / z[0], 1.f / z[1], 1.f / z[2], 1.f / z[3]};
            *(f32x4*)&zsh[row][xq] = zi;
        }
    }
    __syncthreads();

    // reduce Part over 7 slices (half4v), normalize -> op[c][row][xq..xq+3]
    for (int idx = t; idx < 4 * 16 * 14; idx += 256) {
        const int c = idx / (16 * 14), rem = idx % (16 * 14);
        const int row = rem / 14, xq = (rem % 14) * 4;
        const int yy = y0 - 1 + row;
        if (yy >= 0 && yy < 56) {
            const int p = yy * 56 + xq;
            const int i = i0 + c;
            f32x4 s = {0.f, 0.f, 0.f, 0.f};
#pragma unroll
            for (int qs = 0; qs < QS2; ++qs) {
                half4v h = *(const half4v*)
                    &Part[(((size_t)n * QS2 + qs) * NCH + i) * HW + p];
                s[0] += (float)h[0]; s[1] += (float)h[1];
                s[2] += (float)h[2]; s[3] += (float)h[3];
            }
            const f32x4 zi = *(const f32x4*)&zsh[row][xq];
            f32x4 o = {s[0] * zi[0], s[1] * zi[1], s[2] * zi[2], s[3] * zi[3]};
            *(f32x4*)&op[c][row][xq] = o;
        }
    }
    __syncthreads();

    // stencil + BN2 + residual, 4 x per thread (4*14*14 = 784 quads)
    for (int idx = t; idx < 4 * 14 * 14; idx += 256) {
        const int c = idx / (14 * 14), rem = idx % (14 * 14);
        const int y = y0 + rem / 14, xq = (rem % 14) * 4;
        const int i = i0 + c;

        float res[4];
#pragma unroll
        for (int j = 0; j < 4; ++j) {
            const int x = xq + j;
            float acc = 0.f;
#pragma unroll
            for (int dy = -1; dy <= 1; ++dy) {
                const int yy = y + dy;
                if (yy < 0 || yy >= 56) continue;
                const int ly = yy - (y0 - 1);
#pragma unroll
                for (int dx = -1; dx <= 1; ++dx) {
                    const int xx = x + dx;
                    if (xx < 0 || xx >= 56) continue;
                    acc += wsh[c * 9 + (dy + 1) * 3 + (dx + 1)] * op[c][ly][xx];
                }
            }
            res[j] = acc;
        }
        const float sc = rsqrtf(var[i] + EPSV) * gamma[i];
        const float mu = mean[i], bi = beta[i];
        const size_t e = ((size_t)n * NCH + i) * HW + y * 56 + xq;
        const f32x4 lv = *(const f32x4*)&l[e];
        f32x4 o = {(res[0] - mu) * sc + bi + lv[0],
                   (res[1] - mu) * sc + bi + lv[1],
                   (res[2] - mu) * sc + bi + lv[2],
                   (res[3] - mu) * sc + bi + lv[3]};
        *(f32x4*)&out[e] = o;
    }
}

// -------------------------------------------------------------------------------
extern "C" void kernel_launch(void* const* d_in, const int* in_sizes, int n_in,
                              void* d_out, int out_size, void* d_ws, size_t ws_size,
                              hipStream_t stream)
{
    const float* l      = (const float*)d_in[0];
    const float* w_in   = (const float*)d_in[1];
    const float* gamma1 = (const float*)d_in[2];
    const float* beta1  = (const float*)d_in[3];
    const float* mean1  = (const float*)d_in[4];
    const float* var1   = (const float*)d_in[5];
    const float* w_dw   = (const float*)d_in[6];
    const float* gamma2 = (const float*)d_in[7];
    const float* beta2  = (const float*)d_in[8];
    const float* mean2  = (const float*)d_in[9];
    const float* var2   = (const float*)d_in[10];
    float* out = (float*)d_out;

    char* ws = (char*)d_ws;
    const size_t szTheta = (size_t)NB * HW * CRED * 2;        // 1.6 MB
    const size_t szGbt   = (size_t)NB * NCH * HW * 2;         // 3.2 MB
    const size_t szCrow  = (size_t)NB * HW * 4;               // 100 KB
    const size_t szZpt   = (size_t)QS2 * NB * HW * 4;         // 0.7 MB
    const size_t szZp    = (size_t)NB * QS2 * HW * 4;         // 0.7 MB

    unsigned short* theta_bf = (unsigned short*)ws;
    unsigned short* Gbt      = (unsigned short*)(ws + szTheta);
    float* crow   = (float*)(ws + szTheta + szGbt);
    float* zpart  = (float*)(ws + szTheta + szGbt + szCrow);
    float* Zp     = (float*)(ws + szTheta + szGbt + szCrow + szZpt);
    half_t* Part  = (half_t*)(ws + szTheta + szGbt + szCrow + szZpt + szZp);
    (void)ws_size;

    k1_conv1x1<<<dim3(HW / 64, NB), 256, 0, stream>>>(
        l, w_in, gamma1, beta1, mean1, var1, theta_bf, Gbt);

    k2s_stats<<<dim3((HW + 127) / 128, QS2, NB), 256, 0, stream>>>(theta_bf, zpart);

    k2c_combine<<<dim3((NB * HW) / 256), 256, 0, stream>>>(zpart, crow);

    k3f_fused<<<dim3((HW + 127) / 128, QS2, NB), 256, 0, stream>>>(
        theta_bf, Gbt, crow, Part, Zp);

    k34_reduce_dw<<<dim3(4, NCH / 4, NB), 256, 0, stream>>>(
        Part, Zp, l, w_dw, gamma2, beta2, mean2, var2, out);
}

// Round 20
// 86.079 us; speedup vs baseline: 1.4092x; 1.0002x over previous
//
#include <hip/hip_runtime.h>

#define HW   3136
#define NCH  64
#define CRED 32
#define NB   8
#define EPSV 1e-5f
#define QS2  7

// sqrt(log2(e)) — both theta operands scaled => S' = S * log2(e)
#define SQRT_L2E 1.2011224087f
// log2(log2(e))
#define LOG2_L2E 0.5287663729f

typedef __attribute__((ext_vector_type(8))) short short8;
typedef __attribute__((ext_vector_type(4))) float f32x4;
typedef __attribute__((ext_vector_type(2))) float f32x2;
typedef _Float16 half_t;
typedef __attribute__((ext_vector_type(2))) _Float16 half2v;
typedef __attribute__((ext_vector_type(4))) _Float16 half4v;

// may_alias variants for the El write/read pair (kills TBAA reorder license)
typedef short8 __attribute__((may_alias)) short8_ma;
typedef unsigned __attribute__((may_alias)) uint_ma;

#define MFMA_B16 __builtin_amdgcn_mfma_f32_16x16x32_bf16

__device__ __forceinline__ unsigned short f2b(float x) {
    union { float f; unsigned u; } v; v.f = x;
    unsigned r = v.u + 0x7fff + ((v.u >> 16) & 1);
    return (unsigned short)(r >> 16);
}

// raw v_exp_f32: 2^x
__device__ __forceinline__ float ex2(float x) {
#if __has_builtin(__builtin_amdgcn_exp2f)
    return __builtin_amdgcn_exp2f(x);
#else
    float r;
    asm volatile("v_exp_f32 %0, %1" : "=v"(r) : "v"(x));
    return r;
#endif
}

// pack two f32 -> bf16x2 in one instruction
__device__ __forceinline__ unsigned cvtpk(float a, float b) {
    unsigned r;
    asm("v_cvt_pk_bf16_f32 %0, %1, %2" : "=v"(r) : "v"(a), "v"(b));
    return r;
}

// async global->LDS DMA, 16B per lane; dst = wave-uniform base + lane*16
__device__ __forceinline__ void gload_lds16(const void* g, void* l) {
    __builtin_amdgcn_global_load_lds(
        (const __attribute__((address_space(1))) void*)g,
        (__attribute__((address_space(3))) void*)l, 16, 0, 0);
}

// ---- K1: conv1x1 + BN1 + ReLU6 -> Gbt[n][i][p] bf16; theta_bf[n][p][c] scaled --
__global__ __launch_bounds__(256) void k1_conv1x1(
    const float* __restrict__ l, const float* __restrict__ w,
    const float* __restrict__ gamma, const float* __restrict__ beta,
    const float* __restrict__ mean, const float* __restrict__ var,
    unsigned short* __restrict__ theta_bf, unsigned short* __restrict__ Gbt)
{
    __shared__ float Wt[NCH][65];   // Wt[c][i]; reused as G-transpose [i][p]
    __shared__ float Lt[NCH][65];   // Lt[c][j]
    const int t  = threadIdx.x;
    const int n  = blockIdx.y;
    const int p0 = blockIdx.x * 64;

    for (int idx = t; idx < NCH * 64; idx += 256) {
        int c = idx >> 6, j = idx & 63;
        Wt[c][j] = w[j * NCH + c];
        Lt[c][j] = l[((size_t)n * NCH + c) * HW + p0 + j];
    }
    __syncthreads();

    // emit theta_bf[n][p0+p][c0..c0+7], pre-scaled by sqrt(log2 e)
    {
        const int p = t >> 2, c0 = (t & 3) * 8;
        unsigned short pk[8];
#pragma unroll
        for (int j = 0; j < 8; ++j) pk[j] = f2b(Lt[c0 + j][p] * SQRT_L2E);
        *(short8*)&theta_bf[((size_t)n * HW + p0 + p) * CRED + c0] = *(short8*)pk;
    }

    const int i   = t & 63;
    const int pj0 = t >> 6;
    const float mu = mean[i];
    const float sc = rsqrtf(var[i] + EPSV) * gamma[i];
    const float bi = beta[i];

    float acc[16];
#pragma unroll
    for (int k = 0; k < 16; ++k) acc[k] = 0.f;
#pragma unroll
    for (int c = 0; c < NCH; ++c) {
        float wci = Wt[c][i];
#pragma unroll
        for (int k = 0; k < 16; ++k) acc[k] += wci * Lt[c][pj0 + 4 * k];
    }
    __syncthreads();   // all reads of Wt done before reuse

#pragma unroll
    for (int k = 0; k < 16; ++k) {
        float y = (acc[k] - mu) * sc + bi;
        y = fminf(fmaxf(y, 0.f), 6.f);
        Wt[i][pj0 + 4 * k] = y;        // transpose buffer [i][p]
    }
    __syncthreads();

    {
        const int ir = t >> 2, pc = (t & 3) * 16;
        unsigned short pk[16];
#pragma unroll
        for (int j = 0; j < 16; ++j) pk[j] = f2b(Wt[ir][pc + j]);
        unsigned short* dst = &Gbt[((size_t)n * NCH + ir) * HW + p0 + pc];
        *(short8*)&dst[0] = *(short8*)&pk[0];
        *(short8*)&dst[8] = *(short8*)&pk[8];
    }
}

// ---- K2s (MFMA, no LDS): TWO q-groups share the p-fragment stream --------------
// r14-verified structure x2: loads per MFMA halved, two independent MFMA->ex2
// chains for ILP. No LDS, no barriers (first-try-safe kernel class).
__global__ __launch_bounds__(256) void k2s_stats(
    const unsigned short* __restrict__ theta_bf, float* __restrict__ zpart)
{
    const int t = threadIdx.x, w = t >> 6, lane = t & 63;
    const int lo = lane & 15, hi = lane >> 4;
    const int n = blockIdx.z, psp = blockIdx.y;
    const int q0A = blockIdx.x * 128;
    const bool hasB = (q0A + 128 <= HW);
    const int q0B = hasB ? q0A + 64 : q0A;

    const unsigned short* thn = theta_bf + (size_t)n * HW * CRED;

    const short8 afA = *(const short8*)&thn[(q0A + w * 16 + lo) * CRED + hi * 8];
    const short8 afB = *(const short8*)&thn[(q0B + w * 16 + lo) * CRED + hi * 8];

    float zA[4] = {0.f, 0.f, 0.f, 0.f};
    float zB[4] = {0.f, 0.f, 0.f, 0.f};

    short8 bf[4];
    {
        const int p0 = psp * 448;
#pragma unroll
        for (int ss = 0; ss < 4; ++ss)
            bf[ss] = *(const short8*)&thn[(p0 + ss * 16 + lo) * CRED + hi * 8];
    }

    for (int pt = 0; pt < 7; ++pt) {
        // prefetch pt+1 fragments (clamped: pt=6 redundantly reloads pt=6, L1-hit)
        const int pn = psp * 448 + ((pt < 6) ? (pt + 1) * 64 : 6 * 64);
        short8 nf[4];
#pragma unroll
        for (int ss = 0; ss < 4; ++ss)
            nf[ss] = *(const short8*)&thn[(pn + ss * 16 + lo) * CRED + hi * 8];

#pragma unroll
        for (int ss = 0; ss < 4; ++ss) {
            f32x4 zero = {0.f, 0.f, 0.f, 0.f};
            f32x4 dA = MFMA_B16(afA, bf[ss], zero, 0, 0, 0);
            f32x4 dB = MFMA_B16(afB, bf[ss], zero, 0, 0, 0);
#pragma unroll
            for (int r = 0; r < 4; ++r) zA[r] += ex2(dA[r]);
#pragma unroll
            for (int r = 0; r < 4; ++r) zB[r] += ex2(dB[r]);
        }

#pragma unroll
        for (int ss = 0; ss < 4; ++ss) bf[ss] = nf[ss];
    }

#pragma unroll
    for (int r = 0; r < 4; ++r) {
        float vA = zA[r];
        vA += __shfl_xor(vA, 1, 64);
        vA += __shfl_xor(vA, 2, 64);
        vA += __shfl_xor(vA, 4, 64);
        vA += __shfl_xor(vA, 8, 64);
        zA[r] = vA;
        float vB = zB[r];
        vB += __shfl_xor(vB, 1, 64);
        vB += __shfl_xor(vB, 2, 64);
        vB += __shfl_xor(vB, 4, 64);
        vB += __shfl_xor(vB, 8, 64);
        zB[r] = vB;
    }
    if (lo == 0) {
        f32x4 stA = {zA[0], zA[1], zA[2], zA[3]};
        *(f32x4*)&zpart[((size_t)psp * NB + n) * HW + q0A + w * 16 + hi * 4] = stA;
        if (hasB) {
            f32x4 stB = {zB[0], zB[1], zB[2], zB[3]};
            *(f32x4*)&zpart[((size_t)psp * NB + n) * HW + q0B + w * 16 + hi * 4] = stB;
        }
    }
}

// ---- K2c: crow[n][q] = log2(log2 e) - log2(sum_psp zpart) ----------------------
__global__ __launch_bounds__(256) void k2c_combine(
    const float* __restrict__ zpart, float* __restrict__ crow)
{
    const int idx = blockIdx.x * 256 + threadIdx.x;
    float s = 0.f;
#pragma unroll
    for (int ps = 0; ps < QS2; ++ps) s += zpart[(size_t)ps * NB * HW + idx];
    crow[idx] = LOG2_L2E - __log2f(s);
}

// S+PV for one p-group: same verified sequence as r10..r18, parameterized by
// (bp fragment, accumulator, z accumulator). El accesses via may_alias types.
#define S_PV_GRP(BP, ACC, ZL)                                                  \
    do {                                                                       \
        _Pragma("unroll")                                                      \
        for (int s = 0; s < 4; ++s) {                                          \
            f32x4 d = MFMA_B16(aqr[s], BP, cvr[s], 0, 0, 0);                   \
            float e0 = ex2(ex2(d[0]));                                         \
            float e1 = ex2(ex2(d[1]));                                         \
            float e2 = ex2(ex2(d[2]));                                         \
            float e3 = ex2(ex2(d[3]));                                         \
            ZL += (e0 + e1) + (e2 + e3);                                       \
            uint_ma* dst = (uint_ma*)&El[pw + lo][s * 16 + hi * 4];            \
            dst[0] = cvtpk(e0, e1);                                            \
            dst[1] = cvtpk(e2, e3);                                            \
        }                                                                      \
        _Pragma("unroll")                                                      \
        for (int ks = 0; ks < 2; ++ks) {                                       \
            const short8 ae =                                                  \
                *(const short8_ma*)&El[pw + lo][ks * 32 + hi * 8];             \
            _Pragma("unroll")                                                  \
            for (int it = 0; it < 4; ++it) {                                   \
                const int row = it * 16 + lo;                                  \
                const int cc  = (ks * 4 + hi) ^ (row & 7);                     \
                const short8 bg = *(const short8_ma*)&gl[row * 64 + cc * 8];   \
                ACC[it] = MFMA_B16(ae, bg, ACC[it], 0, 0, 0);                  \
            }                                                                  \
        }                                                                      \
    } while (0)

// ---- K3f (MFMA): TWO p-groups per block share G tile, aq/cvr, barriers --------
// r18-verified. FROZEN.
__global__ __launch_bounds__(256) void k3f_fused(
    const unsigned short* __restrict__ theta_bf,
    const unsigned short* __restrict__ Gbt,
    const float* __restrict__ crow,
    half_t* __restrict__ Part, float* __restrict__ Zpart)
{
    __shared__ unsigned short Glt[64][64];   // G^T, linear, src-swizzled
    __shared__ unsigned short El[64][76];    // E [p][q] (wave-private rows)

    const int t = threadIdx.x, w = t >> 6, lane = t & 63;
    const int lo = lane & 15, hi = lane >> 4;
    const int n = blockIdx.z, qsp = blockIdx.y;
    const int pblk = blockIdx.x * 128;
    const bool has2 = (pblk + 128 <= HW);
    const int pblk2 = has2 ? pblk + 64 : pblk;
    const int pw = w * 16;

    const unsigned short* thn = theta_bf + (size_t)n * HW * CRED;
    const float* crn = crow + (size_t)n * HW;
    const unsigned short* gbn = Gbt + (size_t)n * NCH * HW;

    // per-group block-invariant theta_p fragments
    const short8 bp0 = *(const short8*)&thn[(pblk  + pw + lo) * CRED + hi * 8];
    const short8 bp1 = *(const short8*)&thn[(pblk2 + pw + lo) * CRED + hi * 8];

    // chunk ids this lane DMAs (2 per lane, 512 total = 64 rows x 8 chunks)
    const int s0 = (w * 2 + 0) * 64 + lane;
    const int s1 = (w * 2 + 1) * 64 + lane;
    const int r0 = s0 >> 3, j0 = (s0 & 7) ^ (r0 & 7);
    const int r1 = s1 >> 3, j1 = (s1 & 7) ^ (r1 & 7);
    char* lbase = (char*)&Glt[0][0];
    const unsigned short* gl = &Glt[0][0];

    f32x4 accA[4], accB[4];
#pragma unroll
    for (int it = 0; it < 4; ++it) {
        accA[it] = (f32x4){0.f, 0.f, 0.f, 0.f};
        accB[it] = (f32x4){0.f, 0.f, 0.f, 0.f};
    }
    float zlA = 0.f, zlB = 0.f;

    for (int tile = 0; tile < 7; ++tile) {
        const int qb = qsp * 448 + tile * 64;
        __syncthreads();
        // stage G^T tile: async DMA, swizzled source, linear LDS dest
        gload_lds16(&gbn[(size_t)r0 * HW + qb + j0 * 8],
                    lbase + (size_t)(w * 2 + 0) * 1024);
        gload_lds16(&gbn[(size_t)r1 * HW + qb + j1 * 8],
                    lbase + (size_t)(w * 2 + 1) * 1024);
        // aq/crow loads (shared by BOTH p-groups) drain at the barrier below
        short8 aqr[4];
        f32x4  cvr[4];
#pragma unroll
        for (int s = 0; s < 4; ++s) {
            aqr[s] = *(const short8*)&thn[(qb + s * 16 + lo) * CRED + hi * 8];
            cvr[s] = *(const f32x4*)&crn[qb + s * 16 + hi * 4];
        }
        __syncthreads();

        S_PV_GRP(bp0, accA, zlA);
        if (has2) {
            __asm__ __volatile__("" ::: "memory");   // pin El A-reads before B-writes
            S_PV_GRP(bp1, accB, zlB);
        }
    }

    // Part[n,qsp][i][p] fp16 — group A at pblk, group B at pblk+64
    half_t* Pn = Part + ((size_t)n * QS2 + qsp) * (size_t)NCH * HW;
#pragma unroll
    for (int it = 0; it < 4; ++it) {
        half4v h;
        h[0] = (half_t)accA[it][0]; h[1] = (half_t)accA[it][1];
        h[2] = (half_t)accA[it][2]; h[3] = (half_t)accA[it][3];
        *(half4v*)&Pn[(size_t)(it * 16 + lo) * HW + pblk + pw + hi * 4] = h;
    }
    zlA += __shfl_xor(zlA, 16, 64);
    zlA += __shfl_xor(zlA, 32, 64);
    if (lane < 16)
        Zpart[((size_t)n * QS2 + qsp) * HW + pblk + pw + lane] = zlA;

    if (has2) {
#pragma unroll
        for (int it = 0; it < 4; ++it) {
            half4v h;
            h[0] = (half_t)accB[it][0]; h[1] = (half_t)accB[it][1];
            h[2] = (half_t)accB[it][2]; h[3] = (half_t)accB[it][3];
            *(half4v*)&Pn[(size_t)(it * 16 + lo) * HW + pblk + 64 + pw + hi * 4] = h;
        }
        zlB += __shfl_xor(zlB, 16, 64);
        zlB += __shfl_xor(zlB, 32, 64);
        if (lane < 16)
            Zpart[((size_t)n * QS2 + qsp) * HW + pblk + 64 + pw + lane] = zlB;
    }
}

// ---- K34: fused (reduce q-slices + Z-normalize) + depthwise 3x3 + BN2 + res ----
// r16-verified (vectorized).
__global__ __launch_bounds__(256) void k34_reduce_dw(
    const half_t* __restrict__ Part, const float* __restrict__ Zpart,
    const float* __restrict__ l, const float* __restrict__ wdw,
    const float* __restrict__ gamma, const float* __restrict__ beta,
    const float* __restrict__ mean, const float* __restrict__ var,
    float* __restrict__ out)
{
    __shared__ float op[4][16][56];   // normalized OutPre, halo rows
    __shared__ float zsh[16][56];     // 1/Z for halo rows
    __shared__ float wsh[36];         // dw weights for the 4 channels

    const int t    = threadIdx.x;
    const int band = blockIdx.x;            // 0..3, y0 = band*14
    const int i0   = blockIdx.y * 4;        // channel group
    const int n    = blockIdx.z;
    const int y0   = band * 14;

    if (t < 36) wsh[t] = wdw[i0 * 9 + t];

    // 1/Z for halo rows [y0-1, y0+14], 4 x at a time (16*14 = 224 quads)
    if (t < 16 * 14) {
        const int row = t / 14, xq = (t % 14) * 4;
        const int yy = y0 - 1 + row;
        if (yy >= 0 && yy < 56) {
            const int p = yy * 56 + xq;
            f32x4 z = {0.f, 0.f, 0.f, 0.f};
#pragma unroll
            for (int qs = 0; qs < QS2; ++qs)
                z += *(const f32x4*)&Zpart[((size_t)n * QS2 + qs) * HW + p];
            f32x4 zi = {1.f / z[0], 1.f / z[1], 1.f / z[2], 1.f / z[3]};
            *(f32x4*)&zsh[row][xq] = zi;
        }
    }
    __syncthreads();

    // reduce Part over 7 slices (half4v), normalize -> op[c][row][xq..xq+3]
    for (int idx = t; idx < 4 * 16 * 14; idx += 256) {
        const int c = idx / (16 * 14), rem = idx % (16 * 14);
        const int row = rem / 14, xq = (rem % 14) * 4;
        const int yy = y0 - 1 + row;
        if (yy >= 0 && yy < 56) {
            const int p = yy * 56 + xq;
            const int i = i0 + c;
            f32x4 s = {0.f, 0.f, 0.f, 0.f};
#pragma unroll
            for (int qs = 0; qs < QS2; ++qs) {
                half4v h = *(const half4v*)
                    &Part[(((size_t)n * QS2 + qs) * NCH + i) * HW + p];
                s[0] += (float)h[0]; s[1] += (float)h[1];
                s[2] += (float)h[2]; s[3] += (float)h[3];
            }
            const f32x4 zi = *(const f32x4*)&zsh[row][xq];
            f32x4 o = {s[0] * zi[0], s[1] * zi[1], s[2] * zi[2], s[3] * zi[3]};
            *(f32x4*)&op[c][row][xq] = o;
        }
    }
    __syncthreads();

    // stencil + BN2 + residual, 4 x per thread (4*14*14 = 784 quads)
    for (int idx = t; idx < 4 * 14 * 14; idx += 256) {
        const int c = idx / (14 * 14), rem = idx % (14 * 14);
        const int y = y0 + rem / 14, xq = (rem % 14) * 4;
        const int i = i0 + c;

        float res[4];
#pragma unroll
        for (int j = 0; j < 4; ++j) {
            const int x = xq + j;
            float acc = 0.f;
#pragma unroll
            for (int dy = -1; dy <= 1; ++dy) {
                const int yy = y + dy;
                if (yy < 0 || yy >= 56) continue;
                const int ly = yy - (y0 - 1);
#pragma unroll
                for (int dx = -1; dx <= 1; ++dx) {
                    const int xx = x + dx;
                    if (xx < 0 || xx >= 56) continue;
                    acc += wsh[c * 9 + (dy + 1) * 3 + (dx + 1)] * op[c][ly][xx];
                }
            }
            res[j] = acc;
        }
        const float sc = rsqrtf(var[i] + EPSV) * gamma[i];
        const float mu = mean[i], bi = beta[i];
        const size_t e = ((size_t)n * NCH + i) * HW + y * 56 + xq;
        const f32x4 lv = *(const f32x4*)&l[e];
        f32x4 o = {(res[0] - mu) * sc + bi + lv[0],
                   (res[1] - mu) * sc + bi + lv[1],
                   (res[2] - mu) * sc + bi + lv[2],
                   (res[3] - mu) * sc + bi + lv[3]};
        *(f32x4*)&out[e] = o;
    }
}

// -------------------------------------------------------------------------------
extern "C" void kernel_launch(void* const* d_in, const int* in_sizes, int n_in,
                              void* d_out, int out_size, void* d_ws, size_t ws_size,
                              hipStream_t stream)
{
    const float* l      = (const float*)d_in[0];
    const float* w_in   = (const float*)d_in[1];
    const float* gamma1 = (const float*)d_in[2];
    const float* beta1  = (const float*)d_in[3];
    const float* mean1  = (const float*)d_in[4];
    const float* var1   = (const float*)d_in[5];
    const float* w_dw   = (const float*)d_in[6];
    const float* gamma2 = (const float*)d_in[7];
    const float* beta2  = (const float*)d_in[8];
    const float* mean2  = (const float*)d_in[9];
    const float* var2   = (const float*)d_in[10];
    float* out = (float*)d_out;

    char* ws = (char*)d_ws;
    const size_t szTheta = (size_t)NB * HW * CRED * 2;        // 1.6 MB
    const size_t szGbt   = (size_t)NB * NCH * HW * 2;         // 3.2 MB
    const size_t szCrow  = (size_t)NB * HW * 4;               // 100 KB
    const size_t szZpt   = (size_t)QS2 * NB * HW * 4;         // 0.7 MB
    const size_t szZp    = (size_t)NB * QS2 * HW * 4;         // 0.7 MB

    unsigned short* theta_bf = (unsigned short*)ws;
    unsigned short* Gbt      = (unsigned short*)(ws + szTheta);
    float* crow   = (float*)(ws + szTheta + szGbt);
    float* zpart  = (float*)(ws + szTheta + szGbt + szCrow);
    float* Zp     = (float*)(ws + szTheta + szGbt + szCrow + szZpt);
    half_t* Part  = (half_t*)(ws + szTheta + szGbt + szCrow + szZpt + szZp);
    (void)ws_size;

    k1_conv1x1<<<dim3(HW / 64, NB), 256, 0, stream>>>(
        l, w_in, gamma1, beta1, mean1, var1, theta_bf, Gbt);

    k2s_stats<<<dim3((HW + 127) / 128, QS2, NB), 256, 0, stream>>>(theta_bf, zpart);

    k2c_combine<<<dim3((NB * HW) / 256), 256, 0, stream>>>(zpart, crow);

    k3f_fused<<<dim3((HW + 127) / 128, QS2, NB), 256, 0, stream>>>(
        theta_bf, Gbt, crow, Part, Zp);

    k34_reduce_dw<<<dim3(4, NCH / 4, NB), 256, 0, stream>>>(
        Part, Zp, l, w_dw, gamma2, beta2, mean2, var2, out);
}